// Round 13
// baseline (4968.070 us; speedup 1.0000x reference)
//
#include <hip/hip_runtime.h>
#include <hip/hip_bf16.h>
#include <stdint.h>

#define T_STEPS 12
#define NN 20000
#define NE 320000
#define FIN 128
#define HD 256
#define FOUT 128
#define PADR 96  // pad A-panel buffers to 157*128 = 20096 rows

typedef __attribute__((ext_vector_type(4))) float f32x4;
typedef __attribute__((ext_vector_type(8))) _Float16 f16x8;

static __device__ __forceinline__ float sigmoidf_(float x) {
  return 1.0f / (1.0f + __expf(-x));
}
static __device__ __forceinline__ ushort f2h(float f) {
  union { ushort s; _Float16 h; } v; v.h = (_Float16)f; return v.s;
}

// async global -> LDS, 16B per lane, LDS dest = wave-uniform base + lane*16
static __device__ __forceinline__ void gload_lds16(const _Float16* g, _Float16* l) {
  auto gp = (const __attribute__((address_space(1))) _Float16*)g;
  auto lp = (__attribute__((address_space(3))) _Float16*)l;
  __builtin_amdgcn_global_load_lds(gp, lp, 16, 0, 0);
}

// ---------------- CSR build ----------------
__global__ void count_kernel(const int* __restrict__ dst, int* __restrict__ counts) {
  int e = blockIdx.x * blockDim.x + threadIdx.x;
  if (e < NE) atomicAdd(&counts[dst[e]], 1);
}

__global__ void scan_kernel(const int* __restrict__ counts, int* __restrict__ offs,
                            int* __restrict__ cursor) {
  __shared__ int sm[1024];
  __shared__ int carry_s;
  if (threadIdx.x == 0) carry_s = 0;
  __syncthreads();
  const int n = NN;
  int nch = (n + 1023) >> 10;
  for (int c = 0; c < nch; ++c) {
    int i = (c << 10) + (int)threadIdx.x;
    int v = (i < n) ? counts[i] : 0;
    sm[threadIdx.x] = v;
    __syncthreads();
    for (int off = 1; off < 1024; off <<= 1) {
      int t = (threadIdx.x >= (unsigned)off) ? sm[threadIdx.x - off] : 0;
      __syncthreads();
      sm[threadIdx.x] += t;
      __syncthreads();
    }
    int incl = sm[threadIdx.x];
    int carry_local = carry_s;
    if (i < n) {
      int excl = carry_local + incl - v;
      offs[i] = excl;
      cursor[i] = excl;
    }
    __syncthreads();
    if (threadIdx.x == 1023) carry_s = carry_local + incl;
    __syncthreads();
  }
  if (threadIdx.x == 0) offs[n] = carry_s;
}

__global__ void fill_kernel(const int* __restrict__ src, const int* __restrict__ dst,
                            int* __restrict__ cursor, int* __restrict__ esrc) {
  int e = blockIdx.x * blockDim.x + threadIdx.x;
  if (e < NE) {
    int d = dst[e];
    int pos = atomicAdd(&cursor[d], 1);
    esrc[pos] = src[e];
  }
}

// ---------------- agg body: fp32 gather-sum -> fp16 hi/lo (W=256, out ld=512) ----------------
static __device__ __forceinline__ void agg_body256(int blk, const float* __restrict__ feat,
                                                   const int* __restrict__ offs,
                                                   const int* __restrict__ esrc,
                                                   _Float16* __restrict__ out) {
  int d = blk * 4 + (threadIdx.x >> 6);
  int lane = threadIdx.x & 63;
  int beg = offs[d], end = offs[d + 1];
  float a[8][4] = {};
  int e = beg;
  for (; e + 7 < end; e += 8) {
#pragma unroll
    for (int u = 0; u < 8; ++u) {
      float4 v = *reinterpret_cast<const float4*>(feat + (size_t)esrc[e + u] * 256 + lane * 4);
      a[u][0] += v.x; a[u][1] += v.y; a[u][2] += v.z; a[u][3] += v.w;
    }
  }
  for (; e + 3 < end; e += 4) {
#pragma unroll
    for (int u = 0; u < 4; ++u) {
      float4 v = *reinterpret_cast<const float4*>(feat + (size_t)esrc[e + u] * 256 + lane * 4);
      a[u][0] += v.x; a[u][1] += v.y; a[u][2] += v.z; a[u][3] += v.w;
    }
  }
  for (; e < end; ++e) {
    float4 v = *reinterpret_cast<const float4*>(feat + (size_t)esrc[e] * 256 + lane * 4);
    a[0][0] += v.x; a[0][1] += v.y; a[0][2] += v.z; a[0][3] += v.w;
  }
  ushort hi[4], lo[4];
#pragma unroll
  for (int p = 0; p < 4; ++p) {
    float s = ((a[0][p] + a[1][p]) + (a[2][p] + a[3][p])) +
              ((a[4][p] + a[5][p]) + (a[6][p] + a[7][p]));
    hi[p] = f2h(s);
    union { ushort us; _Float16 h; } u; u.us = hi[p];
    lo[p] = f2h(s - (float)u.h);
  }
  *reinterpret_cast<ushort4*>(out + (size_t)d * 512 + lane * 4) = *reinterpret_cast<ushort4*>(hi);
  *reinterpret_cast<ushort4*>(out + (size_t)d * 512 + 256 + lane * 4) = *reinterpret_cast<ushort4*>(lo);
}

__global__ void agg_split_h(const float* __restrict__ feat, const int* __restrict__ offs,
                            const int* __restrict__ esrc, _Float16* __restrict__ out) {
  agg_body256(blockIdx.x, feat, offs, esrc, out);
}

// dual agg: two independent gathers in one launch (like-resourced merge only)
__global__ void agg_dual(const float* __restrict__ f0, _Float16* __restrict__ o0,
                         const float* __restrict__ f1, _Float16* __restrict__ o1,
                         const int* __restrict__ offs, const int* __restrict__ esrc) {
  if (blockIdx.y == 0) agg_body256(blockIdx.x, f0, offs, esrc, o0);
  else                 agg_body256(blockIdx.x, f1, offs, esrc, o1);
}

// batched x-aggregation over all T steps: grid (NN/4, T); out [t][N][256] = [hi128|lo128]
__global__ void agg_split_x(const float* __restrict__ x, const int* __restrict__ offs,
                            const int* __restrict__ esrc, _Float16* __restrict__ out) {
  int t = blockIdx.y;
  const float* feat = x + (size_t)t * NN * FIN;
  _Float16* o = out + (size_t)t * NN * 256;
  int d = blockIdx.x * 4 + (threadIdx.x >> 6);
  int lane = threadIdx.x & 63;
  int beg = offs[d], end = offs[d + 1];
  float a[8][2] = {};
  int e = beg;
  for (; e + 7 < end; e += 8) {
#pragma unroll
    for (int u = 0; u < 8; ++u) {
      float2 v = *reinterpret_cast<const float2*>(feat + (size_t)esrc[e + u] * FIN + lane * 2);
      a[u][0] += v.x; a[u][1] += v.y;
    }
  }
  for (; e + 3 < end; e += 4) {
#pragma unroll
    for (int u = 0; u < 4; ++u) {
      float2 v = *reinterpret_cast<const float2*>(feat + (size_t)esrc[e + u] * FIN + lane * 2);
      a[u][0] += v.x; a[u][1] += v.y;
    }
  }
  for (; e < end; ++e) {
    float2 v = *reinterpret_cast<const float2*>(feat + (size_t)esrc[e] * FIN + lane * 2);
    a[0][0] += v.x; a[0][1] += v.y;
  }
  float s0 = ((a[0][0] + a[1][0]) + (a[2][0] + a[3][0])) +
             ((a[4][0] + a[5][0]) + (a[6][0] + a[7][0]));
  float s1 = ((a[0][1] + a[1][1]) + (a[2][1] + a[3][1])) +
             ((a[4][1] + a[5][1]) + (a[6][1] + a[7][1]));
  ushort2 hi, lo;
  hi.x = f2h(s0); hi.y = f2h(s1);
  union { ushort s; _Float16 h; } u0, u1;
  u0.s = hi.x; u1.s = hi.y;
  lo.x = f2h(s0 - (float)u0.h); lo.y = f2h(s1 - (float)u1.h);
  *reinterpret_cast<ushort2*>(o + (size_t)d * 256 + lane * 2) = hi;
  *reinterpret_cast<ushort2*>(o + (size_t)d * 256 + FIN + lane * 2) = lo;
}

// ---------------- GEMM params + body (R12 staging, R11 Cacc, single inline site) ----
// mode 0: C = acc + bias. mode 1 (fused r/u): v = acc + (Cacc ? Cacc_row : bias);
// cols<256 -> rh=sigmoid(v)*h; 256..511 -> C=sigmoid(v); >=512 -> C=v.
// mode 2: nh = u*h + (1-u)*tanh(xw_c + acc) -> h (+hf mirror).
// A-panel sources MUST be padded to 20096 rows; epilogue masks m<M.
struct GemmP {
  const _Float16* Aa; int lda_a, wrapA, lenA;
  const _Float16* Ab; int lda_b, wrapB;
  const _Float16* B; int ldb;
  float* C; int ldc;
  const float* bias;
  const float* Cacc;
  int M, K, mode;
  float* h; _Float16* hf; float* rh;
  int nch, rpg;
};

static __device__ __forceinline__ void gemm_body(int p, const GemmP& g,
                                                 _Float16* As, _Float16* Bs) {
  int xcd = p & 7;
  int q = p >> 3;
  int rowt = xcd * g.rpg + q / g.nch;
  int chunk = q % g.nch;
  int m0 = rowt * 128;
  if (m0 >= g.M) return;
  int n0 = chunk * 128;

  int tid = threadIdx.x;
  int wave = tid >> 6;
  int lane = tid & 63;
  int wm = wave >> 1, wn = wave & 1;
  int lrow = lane & 15;
  int kgrp = lane >> 4;

  f32x4 acc[4][4] = {};

  // staging: linear LDS write (base + lane*16); XOR swizzle pre-applied to GLOBAL col
  int row8 = lane >> 3;
  int swz8 = 8 * ((lane & 7) ^ row8);
  int wrow = wave * 32;

  for (int k0 = 0; k0 < g.K; k0 += 64) {
    const _Float16* Abase;
    int ka, ldA;
    if (k0 < g.lenA) {
      ka = (k0 >= g.wrapA) ? k0 - g.wrapA : k0;
      Abase = g.Aa; ldA = g.lda_a;
    } else {
      int kp = k0 - g.lenA;
      ka = (kp >= g.wrapB) ? kp - g.wrapB : kp;
      Abase = g.Ab; ldA = g.lda_b;
    }
    __syncthreads();
#pragma unroll
    for (int p4 = 0; p4 < 4; ++p4) {
      int r = wrow + p4 * 8;
      gload_lds16(&Abase[(size_t)(m0 + r + row8) * ldA + ka + swz8], &As[r * 64]);
      gload_lds16(&g.B[(size_t)(n0 + r + row8) * g.ldb + k0 + swz8], &Bs[r * 64]);
    }
    __syncthreads();

#pragma unroll
    for (int kk = 0; kk < 2; ++kk) {
      f16x8 af[4], bf[4];
      int kbyte = kk * 64 + kgrp * 16;
#pragma unroll
      for (int i = 0; i < 4; ++i) {
        int ar = wm * 64 + i * 16 + lrow;
        af[i] = *reinterpret_cast<const f16x8*>(
            reinterpret_cast<const char*>(As) + ar * 128 + (kbyte ^ ((ar & 7) << 4)));
        int br = wn * 64 + i * 16 + lrow;
        bf[i] = *reinterpret_cast<const f16x8*>(
            reinterpret_cast<const char*>(Bs) + br * 128 + (kbyte ^ ((br & 7) << 4)));
      }
#pragma unroll
      for (int i = 0; i < 4; ++i)
#pragma unroll
        for (int j = 0; j < 4; ++j)
          acc[i][j] = __builtin_amdgcn_mfma_f32_16x16x32_f16(bf[j], af[i], acc[i][j], 0, 0, 0);
    }
  }

#pragma unroll
  for (int i = 0; i < 4; ++i) {
    int m = m0 + wm * 64 + i * 16 + lrow;
    if (m >= g.M) continue;
#pragma unroll
    for (int j = 0; j < 4; ++j) {
      int colbase = n0 + wn * 64 + j * 16 + kgrp * 4;
      f32x4 v = acc[i][j];
      if (g.mode == 0) {
        float4 bv4 = *reinterpret_cast<const float4*>(&g.bias[colbase]);
        v[0] += bv4.x; v[1] += bv4.y; v[2] += bv4.z; v[3] += bv4.w;
        *reinterpret_cast<f32x4*>(&g.C[(size_t)m * g.ldc + colbase]) = v;
      } else if (g.mode == 1) {
        if (g.Cacc) {
          float4 a4 = *reinterpret_cast<const float4*>(&g.Cacc[(size_t)m * g.ldc + colbase]);
          v[0] += a4.x; v[1] += a4.y; v[2] += a4.z; v[3] += a4.w;
        } else {
          float4 bv4 = *reinterpret_cast<const float4*>(&g.bias[colbase]);
          v[0] += bv4.x; v[1] += bv4.y; v[2] += bv4.z; v[3] += bv4.w;
        }
        if (colbase < 256) {
          float4 hv = *reinterpret_cast<const float4*>(&g.h[(size_t)m * 256 + colbase]);
          f32x4 rv;
          rv[0] = sigmoidf_(v[0]) * hv.x;
          rv[1] = sigmoidf_(v[1]) * hv.y;
          rv[2] = sigmoidf_(v[2]) * hv.z;
          rv[3] = sigmoidf_(v[3]) * hv.w;
          *reinterpret_cast<f32x4*>(&g.rh[(size_t)m * 256 + colbase]) = rv;
        } else if (colbase < 512) {
          v[0] = sigmoidf_(v[0]); v[1] = sigmoidf_(v[1]);
          v[2] = sigmoidf_(v[2]); v[3] = sigmoidf_(v[3]);
          *reinterpret_cast<f32x4*>(&g.C[(size_t)m * g.ldc + colbase]) = v;
        } else {
          *reinterpret_cast<f32x4*>(&g.C[(size_t)m * g.ldc + colbase]) = v;
        }
      } else {
        float4 xc = *reinterpret_cast<const float4*>(&g.C[(size_t)m * g.ldc + 512 + colbase]);
        float4 uu = *reinterpret_cast<const float4*>(&g.C[(size_t)m * g.ldc + 256 + colbase]);
        float* hp = &g.h[(size_t)m * 256 + colbase];
        float4 hv = *reinterpret_cast<const float4*>(hp);
        float4 nh;
        nh.x = uu.x * hv.x + (1.f - uu.x) * tanhf(xc.x + v[0]);
        nh.y = uu.y * hv.y + (1.f - uu.y) * tanhf(xc.y + v[1]);
        nh.z = uu.z * hv.z + (1.f - uu.z) * tanhf(xc.z + v[2]);
        nh.w = uu.w * hv.w + (1.f - uu.w) * tanhf(xc.w + v[3]);
        *reinterpret_cast<float4*>(hp) = nh;
        if (g.hf) {
          ushort4 hv16;
          hv16.x = f2h(nh.x); hv16.y = f2h(nh.y);
          hv16.z = f2h(nh.z); hv16.w = f2h(nh.w);
          *reinterpret_cast<ushort4*>(&g.hf[(size_t)m * 256 + colbase]) = hv16;
        }
      }
    }
  }
}

// combo: up to 3 GEMMs per launch. SINGLE gemm_body inline site (R11 lesson:
// three inlined copies shared regalloc -> VGPR 132; uniform select keeps it flat).
__global__ __launch_bounds__(256) void combo(GemmP ga, int na, GemmP gb, int nb, GemmP gc) {
  __shared__ _Float16 As[128 * 64];
  __shared__ _Float16 Bs[128 * 64];
  int b = blockIdx.x;
  int sel = (b < na) ? 0 : ((b < na + nb) ? 1 : 2);
  int idx = b - ((sel > 0) ? na : 0) - ((sel > 1) ? nb : 0);
  GemmP g = (sel == 0) ? ga : ((sel == 1) ? gb : gc);
  gemm_body(idx, g, As, Bs);
}

// ---------------- weight prep ----------------
__global__ void wtrans(const float* __restrict__ W, _Float16* __restrict__ dst,
                       int K, int ldw, int ldd, int koff, int mode) {
  int k = blockIdx.x * blockDim.x + threadIdx.x;
  int n = blockIdx.y;
  if (k < K) {
    float w = W[(size_t)k * ldw + n];
    _Float16 hi = (_Float16)w;
    dst[(size_t)n * ldd + koff + k] = mode ? (_Float16)(w - (float)hi) : hi;
  }
}

__global__ void bias_comb(const float* __restrict__ bx, const float* __restrict__ bh,
                          float* __restrict__ out) {
  int i = blockIdx.x * blockDim.x + threadIdx.x;
  if (i < 768) out[i] = bx[i] + bh[i];
}

__global__ void copy_kernel(const float* __restrict__ in, float* __restrict__ out, int n4) {
  int i = blockIdx.x * blockDim.x + threadIdx.x;
  if (i < n4) reinterpret_cast<float4*>(out)[i] = reinterpret_cast<const float4*>(in)[i];
}

// ---------------- host ----------------
extern "C" void kernel_launch(void* const* d_in, const int* in_sizes, int n_in,
                              void* d_out, int out_size, void* d_ws, size_t ws_size,
                              hipStream_t stream) {
  const float* x   = (const float*)d_in[0];
  const float* h0  = (const float*)d_in[1];
  const int*   src = (const int*)d_in[2];
  const int*   dst = (const int*)d_in[3];
  const float* Wx0 = (const float*)d_in[4];
  const float* bx0 = (const float*)d_in[5];
  const float* Wh0 = (const float*)d_in[6];
  const float* bh0 = (const float*)d_in[7];
  const float* Wx1 = (const float*)d_in[8];
  const float* bx1 = (const float*)d_in[9];
  const float* Wh1 = (const float*)d_in[10];
  const float* bh1 = (const float*)d_in[11];
  const float* Wo  = (const float*)d_in[12];
  const float* bo  = (const float*)d_in[13];
  float* out = (float*)d_out;

  char* p = (char*)d_ws;
  auto alloc = [&](size_t bytes) {
    char* r = p;
    p += (bytes + 255) & ~(size_t)255;
    return r;
  };
  int* offs   = (int*)alloc((NN + 1) * sizeof(int));
  int* cursor = (int*)alloc(NN * sizeof(int));
  int* counts = (int*)alloc(NN * sizeof(int));
  int* esrc   = (int*)alloc(NE * sizeof(int));
  _Float16* B0  = (_Float16*)alloc((size_t)768 * 1152 * 2);
  _Float16* B0h = (_Float16*)alloc((size_t)256 * 768 * 2);
  _Float16* B1  = (_Float16*)alloc((size_t)768 * 1536 * 2);
  _Float16* B1h = (_Float16*)alloc((size_t)256 * 768 * 2);
  _Float16* Bo  = (_Float16*)alloc((size_t)128 * 256 * 2);
  float* b0c  = (float*)alloc(768 * 4);
  float* b1c  = (float*)alloc(768 * 4);
  _Float16* XAGG  = (_Float16*)alloc(((size_t)T_STEPS * NN + PADR) * 256 * 2);
  _Float16* H0AGG = (_Float16*)alloc((size_t)(NN + PADR) * 512 * 2);
  _Float16* H1AGG = (_Float16*)alloc((size_t)(NN + PADR) * 512 * 2);
  _Float16* RHAGG = (_Float16*)alloc((size_t)(NN + PADR) * 512 * 2);
  _Float16* h1f   = (_Float16*)alloc((size_t)(NN + PADR) * 256 * 2);
  float* rhf  = (float*)alloc((size_t)NN * 256 * 4);
  float* xw0  = (float*)alloc((size_t)NN * 768 * 4);
  float* xw1  = (float*)alloc((size_t)NN * 768 * 4);

  float* h0c = out + (size_t)T_STEPS * NN * FOUT;
  float* h1c = h0c + (size_t)NN * HD;

  // CSR
  hipMemsetAsync(counts, 0, NN * sizeof(int), stream);
  count_kernel<<<(NE + 255) / 256, 256, 0, stream>>>(dst, counts);
  scan_kernel<<<1, 1024, 0, stream>>>(counts, offs, cursor);
  fill_kernel<<<(NE + 255) / 256, 256, 0, stream>>>(src, dst, cursor, esrc);

  // weight prep (c-gate rows keep all-zero h-part; c h-term via B0h/B1h GEMM)
  hipMemsetAsync(B0, 0, (size_t)768 * 1152 * 2, stream);
  hipMemsetAsync(B1, 0, (size_t)768 * 1536 * 2, stream);
  for (int g = 0; g < 3; ++g) {
    const float* W = Wx0 + (size_t)g * 128 * 256;
    _Float16* D = B0 + (size_t)g * 256 * 1152;
    wtrans<<<dim3(1, 256), 256, 0, stream>>>(W, D, 128, 256, 1152, 0, 0);
    wtrans<<<dim3(1, 256), 256, 0, stream>>>(W, D, 128, 256, 1152, 128, 0);
    wtrans<<<dim3(1, 256), 256, 0, stream>>>(W, D, 128, 256, 1152, 256, 1);
  }
  for (int g = 0; g < 2; ++g) {
    const float* W = Wh0 + (size_t)g * 256 * 256;
    _Float16* D = B0 + (size_t)g * 256 * 1152;
    wtrans<<<dim3(1, 256), 256, 0, stream>>>(W, D, 256, 256, 1152, 384, 0);
    wtrans<<<dim3(1, 256), 256, 0, stream>>>(W, D, 256, 256, 1152, 640, 0);
    wtrans<<<dim3(1, 256), 256, 0, stream>>>(W, D, 256, 256, 1152, 896, 1);
  }
  {
    const float* W = Wh0 + (size_t)2 * 256 * 256;
    wtrans<<<dim3(1, 256), 256, 0, stream>>>(W, B0h, 256, 256, 768, 0, 0);
    wtrans<<<dim3(1, 256), 256, 0, stream>>>(W, B0h, 256, 256, 768, 256, 0);
    wtrans<<<dim3(1, 256), 256, 0, stream>>>(W, B0h, 256, 256, 768, 512, 1);
  }
  for (int g = 0; g < 3; ++g) {
    const float* W = Wx1 + (size_t)g * 256 * 256;
    _Float16* D = B1 + (size_t)g * 256 * 1536;
    wtrans<<<dim3(1, 256), 256, 0, stream>>>(W, D, 256, 256, 1536, 0, 0);
    wtrans<<<dim3(1, 256), 256, 0, stream>>>(W, D, 256, 256, 1536, 256, 0);
    wtrans<<<dim3(1, 256), 256, 0, stream>>>(W, D, 256, 256, 1536, 512, 1);
  }
  for (int g = 0; g < 2; ++g) {
    const float* W = Wh1 + (size_t)g * 256 * 256;
    _Float16* D = B1 + (size_t)g * 256 * 1536;
    wtrans<<<dim3(1, 256), 256, 0, stream>>>(W, D, 256, 256, 1536, 768, 0);
    wtrans<<<dim3(1, 256), 256, 0, stream>>>(W, D, 256, 256, 1536, 1024, 0);
    wtrans<<<dim3(1, 256), 256, 0, stream>>>(W, D, 256, 256, 1536, 1280, 1);
  }
  {
    const float* W = Wh1 + (size_t)2 * 256 * 256;
    wtrans<<<dim3(1, 256), 256, 0, stream>>>(W, B1h, 256, 256, 768, 0, 0);
    wtrans<<<dim3(1, 256), 256, 0, stream>>>(W, B1h, 256, 256, 768, 256, 0);
    wtrans<<<dim3(1, 256), 256, 0, stream>>>(W, B1h, 256, 256, 768, 512, 1);
  }
  wtrans<<<dim3(1, 128), 256, 0, stream>>>(Wo, Bo, 256, 128, 256, 0, 0);
  bias_comb<<<3, 256, 0, stream>>>(bx0, bh0, b0c);
  bias_comb<<<3, 256, 0, stream>>>(bx1, bh1, b1c);

  copy_kernel<<<(2 * NN * HD / 4 + 255) / 256, 256, 0, stream>>>(h0, h0c, 2 * NN * HD / 4);

  dim3 blk(256);
  const int RPG = 20;
  int g6 = 8 * RPG * 6, g2 = 8 * RPG * 2, g1 = 8 * RPG * 1;
  int agg_grid = NN / 4;

  agg_split_x<<<dim3(agg_grid, T_STEPS), blk, 0, stream>>>(x, offs, esrc, XAGG);
  agg_split_h<<<agg_grid, blk, 0, stream>>>(h0c, offs, esrc, H0AGG);

  GemmP dummy = {};
  dummy.nch = 1; dummy.rpg = 1;  // M=0 -> early return

  for (int t = 0; t < T_STEPS; ++t) {
    // ---- A: C1_{t-1} (deferred, RHAGG from F of t-1) ∥ L0_t ----
    GemmP C1p = {RHAGG, 512, 512, 768, nullptr, 0, 0, B1h, 768, xw1, 768, nullptr, nullptr,
                 NN, 768, 2, h1c, h1f, nullptr, 2, RPG};
    GemmP L0p = {XAGG + (size_t)t * NN * 256, 256, 256, 384, H0AGG, 512, 512,
                 B0, 1152, xw0, 768, b0c, nullptr, NN, 1152, 1, h0c, nullptr, rhf, 6, RPG};
    if (t == 0)
      combo<<<g6, blk, 0, stream>>>(L0p, g6, dummy, 0, dummy);
    else
      combo<<<g2 + g6, blk, 0, stream>>>(C1p, g2, L0p, g6, dummy);

    // ---- B: agg(rhf→RHAGG) ∥ agg(h1c→H1AGG) ----
    agg_dual<<<dim3(agg_grid, 2), blk, 0, stream>>>(rhf, RHAGG, h1c, H1AGG, offs, esrc);

    // ---- C: C0_t ∥ L1a_t (H1AGG×Wh1 + b1c → xw1) ∥ OP_{t-1} ----
    GemmP C0p = {RHAGG, 512, 512, 768, nullptr, 0, 0, B0h, 768, xw0, 768, nullptr, nullptr,
                 NN, 768, 2, h0c, nullptr, nullptr, 2, RPG};
    GemmP L1a = {H1AGG, 512, 512, 768, nullptr, 0, 0, B1 + 768, 1536, xw1, 768, b1c, nullptr,
                 NN, 768, 0, nullptr, nullptr, nullptr, 6, RPG};
    GemmP OPp = {h1f, 256, 256, 256, nullptr, 0, 0, Bo, 256,
                 out + (size_t)(t > 0 ? t - 1 : 0) * NN * FOUT, FOUT, bo, nullptr,
                 NN, 256, 0, nullptr, nullptr, nullptr, 1, RPG};
    if (t == 0)
      combo<<<g2 + g6, blk, 0, stream>>>(C0p, g2, L1a, g6, dummy);
    else
      combo<<<g2 + g6 + g1, blk, 0, stream>>>(C0p, g2, L1a, g6, OPp);

    // ---- D: agg(h0c→H0AGG)  (feeds L1b_t and L0_{t+1}) ----
    agg_split_h<<<agg_grid, blk, 0, stream>>>(h0c, offs, esrc, H0AGG);

    // ---- E: L1b_t (H0AGG×Wx1, Cacc=xw1 in place, fused r/u) ----
    GemmP L1b = {H0AGG, 512, 512, 768, nullptr, 0, 0, B1, 1536, xw1, 768, nullptr, xw1,
                 NN, 768, 1, h1c, nullptr, rhf, 6, RPG};
    combo<<<g6, blk, 0, stream>>>(L1b, g6, dummy, 0, dummy);

    // ---- F: agg(rhf→RHAGG)  (feeds C1_t in next step's A) ----
    agg_split_h<<<agg_grid, blk, 0, stream>>>(rhf, offs, esrc, RHAGG);
  }

  // epilogue: C1_{T-1}, then OP_{T-1}
  GemmP C1f = {RHAGG, 512, 512, 768, nullptr, 0, 0, B1h, 768, xw1, 768, nullptr, nullptr,
               NN, 768, 2, h1c, h1f, nullptr, 2, RPG};
  combo<<<g2, blk, 0, stream>>>(C1f, g2, dummy, 0, dummy);
  GemmP OPl = {h1f, 256, 256, 256, nullptr, 0, 0, Bo, 256,
               out + (size_t)(T_STEPS - 1) * NN * FOUT, FOUT, bo, nullptr,
               NN, 256, 0, nullptr, nullptr, nullptr, 1, RPG};
  combo<<<g1, blk, 0, stream>>>(OPl, g1, dummy, 0, dummy);
}

// Round 14
// 4813.081 us; speedup vs baseline: 1.0322x; 1.0322x over previous
//
#include <hip/hip_runtime.h>
#include <hip/hip_bf16.h>
#include <stdint.h>

#define T_STEPS 12
#define NN 20000
#define NE 320000
#define FIN 128
#define HD 256
#define FOUT 128
#define PADR 96  // pad A-panel buffers to 157*128 = 20096 rows

typedef __attribute__((ext_vector_type(4))) float f32x4;
typedef __attribute__((ext_vector_type(8))) _Float16 f16x8;

static __device__ __forceinline__ float sigmoidf_(float x) {
  return 1.0f / (1.0f + __expf(-x));
}
// fast tanh: 1 - 2/(e^{2x}+1); rel err ~1e-7, saturates correctly
static __device__ __forceinline__ float tanhf_(float x) {
  return 1.0f - 2.0f / (__expf(2.0f * x) + 1.0f);
}
static __device__ __forceinline__ ushort f2h(float f) {
  union { ushort s; _Float16 h; } v; v.h = (_Float16)f; return v.s;
}

// async global -> LDS, 16B per lane, LDS dest = wave-uniform base + lane*16
static __device__ __forceinline__ void gload_lds16(const _Float16* g, _Float16* l) {
  auto gp = (const __attribute__((address_space(1))) _Float16*)g;
  auto lp = (__attribute__((address_space(3))) _Float16*)l;
  __builtin_amdgcn_global_load_lds(gp, lp, 16, 0, 0);
}

// ---------------- CSR build ----------------
__global__ void count_kernel(const int* __restrict__ dst, int* __restrict__ counts) {
  int e = blockIdx.x * blockDim.x + threadIdx.x;
  if (e < NE) atomicAdd(&counts[dst[e]], 1);
}

__global__ void scan_kernel(const int* __restrict__ counts, int* __restrict__ offs,
                            int* __restrict__ cursor) {
  __shared__ int sm[1024];
  __shared__ int carry_s;
  if (threadIdx.x == 0) carry_s = 0;
  __syncthreads();
  const int n = NN;
  int nch = (n + 1023) >> 10;
  for (int c = 0; c < nch; ++c) {
    int i = (c << 10) + (int)threadIdx.x;
    int v = (i < n) ? counts[i] : 0;
    sm[threadIdx.x] = v;
    __syncthreads();
    for (int off = 1; off < 1024; off <<= 1) {
      int t = (threadIdx.x >= (unsigned)off) ? sm[threadIdx.x - off] : 0;
      __syncthreads();
      sm[threadIdx.x] += t;
      __syncthreads();
    }
    int incl = sm[threadIdx.x];
    int carry_local = carry_s;
    if (i < n) {
      int excl = carry_local + incl - v;
      offs[i] = excl;
      cursor[i] = excl;
    }
    __syncthreads();
    if (threadIdx.x == 1023) carry_s = carry_local + incl;
    __syncthreads();
  }
  if (threadIdx.x == 0) offs[n] = carry_s;
}

__global__ void fill_kernel(const int* __restrict__ src, const int* __restrict__ dst,
                            int* __restrict__ cursor, int* __restrict__ esrc) {
  int e = blockIdx.x * blockDim.x + threadIdx.x;
  if (e < NE) {
    int d = dst[e];
    int pos = atomicAdd(&cursor[d], 1);
    esrc[pos] = src[e];
  }
}

// ---------------- agg body: fp32 gather-sum -> fp16 hi/lo (W=256, out ld=512) ----------------
// edge indices are wave-uniform -> readfirstlane to SGPR (saves per-lane 64b addr math)
static __device__ __forceinline__ void agg_body256(int blk, const float* __restrict__ feat,
                                                   const int* __restrict__ offs,
                                                   const int* __restrict__ esrc,
                                                   _Float16* __restrict__ out) {
  int d = blk * 4 + (threadIdx.x >> 6);
  int lane = threadIdx.x & 63;
  int beg = offs[d], end = offs[d + 1];
  float a[8][4] = {};
  int e = beg;
  for (; e + 7 < end; e += 8) {
    int s[8];
#pragma unroll
    for (int u = 0; u < 8; ++u) s[u] = __builtin_amdgcn_readfirstlane(esrc[e + u]);
#pragma unroll
    for (int u = 0; u < 8; ++u) {
      float4 v = *reinterpret_cast<const float4*>(feat + (size_t)s[u] * 256 + lane * 4);
      a[u][0] += v.x; a[u][1] += v.y; a[u][2] += v.z; a[u][3] += v.w;
    }
  }
  for (; e + 3 < end; e += 4) {
    int s[4];
#pragma unroll
    for (int u = 0; u < 4; ++u) s[u] = __builtin_amdgcn_readfirstlane(esrc[e + u]);
#pragma unroll
    for (int u = 0; u < 4; ++u) {
      float4 v = *reinterpret_cast<const float4*>(feat + (size_t)s[u] * 256 + lane * 4);
      a[u][0] += v.x; a[u][1] += v.y; a[u][2] += v.z; a[u][3] += v.w;
    }
  }
  for (; e < end; ++e) {
    int s0 = __builtin_amdgcn_readfirstlane(esrc[e]);
    float4 v = *reinterpret_cast<const float4*>(feat + (size_t)s0 * 256 + lane * 4);
    a[0][0] += v.x; a[0][1] += v.y; a[0][2] += v.z; a[0][3] += v.w;
  }
  ushort hi[4], lo[4];
#pragma unroll
  for (int p = 0; p < 4; ++p) {
    float s = ((a[0][p] + a[1][p]) + (a[2][p] + a[3][p])) +
              ((a[4][p] + a[5][p]) + (a[6][p] + a[7][p]));
    hi[p] = f2h(s);
    union { ushort us; _Float16 h; } u; u.us = hi[p];
    lo[p] = f2h(s - (float)u.h);
  }
  *reinterpret_cast<ushort4*>(out + (size_t)d * 512 + lane * 4) = *reinterpret_cast<ushort4*>(hi);
  *reinterpret_cast<ushort4*>(out + (size_t)d * 512 + 256 + lane * 4) = *reinterpret_cast<ushort4*>(lo);
}

__global__ void agg_split_h(const float* __restrict__ feat, const int* __restrict__ offs,
                            const int* __restrict__ esrc, _Float16* __restrict__ out) {
  agg_body256(blockIdx.x, feat, offs, esrc, out);
}

// dual agg: two independent gathers in one launch (like-resourced merge only)
__global__ void agg_dual(const float* __restrict__ f0, _Float16* __restrict__ o0,
                         const float* __restrict__ f1, _Float16* __restrict__ o1,
                         const int* __restrict__ offs, const int* __restrict__ esrc) {
  if (blockIdx.y == 0) agg_body256(blockIdx.x, f0, offs, esrc, o0);
  else                 agg_body256(blockIdx.x, f1, offs, esrc, o1);
}

// batched x-aggregation over all T steps: grid (NN/4, T); out [t][N][256] = [hi128|lo128]
__global__ void agg_split_x(const float* __restrict__ x, const int* __restrict__ offs,
                            const int* __restrict__ esrc, _Float16* __restrict__ out) {
  int t = blockIdx.y;
  const float* feat = x + (size_t)t * NN * FIN;
  _Float16* o = out + (size_t)t * NN * 256;
  int d = blockIdx.x * 4 + (threadIdx.x >> 6);
  int lane = threadIdx.x & 63;
  int beg = offs[d], end = offs[d + 1];
  float a[8][2] = {};
  int e = beg;
  for (; e + 7 < end; e += 8) {
    int s[8];
#pragma unroll
    for (int u = 0; u < 8; ++u) s[u] = __builtin_amdgcn_readfirstlane(esrc[e + u]);
#pragma unroll
    for (int u = 0; u < 8; ++u) {
      float2 v = *reinterpret_cast<const float2*>(feat + (size_t)s[u] * FIN + lane * 2);
      a[u][0] += v.x; a[u][1] += v.y;
    }
  }
  for (; e + 3 < end; e += 4) {
    int s[4];
#pragma unroll
    for (int u = 0; u < 4; ++u) s[u] = __builtin_amdgcn_readfirstlane(esrc[e + u]);
#pragma unroll
    for (int u = 0; u < 4; ++u) {
      float2 v = *reinterpret_cast<const float2*>(feat + (size_t)s[u] * FIN + lane * 2);
      a[u][0] += v.x; a[u][1] += v.y;
    }
  }
  for (; e < end; ++e) {
    int s0 = __builtin_amdgcn_readfirstlane(esrc[e]);
    float2 v = *reinterpret_cast<const float2*>(feat + (size_t)s0 * FIN + lane * 2);
    a[0][0] += v.x; a[0][1] += v.y;
  }
  float s0 = ((a[0][0] + a[1][0]) + (a[2][0] + a[3][0])) +
             ((a[4][0] + a[5][0]) + (a[6][0] + a[7][0]));
  float s1 = ((a[0][1] + a[1][1]) + (a[2][1] + a[3][1])) +
             ((a[4][1] + a[5][1]) + (a[6][1] + a[7][1]));
  ushort2 hi, lo;
  hi.x = f2h(s0); hi.y = f2h(s1);
  union { ushort s; _Float16 h; } u0, u1;
  u0.s = hi.x; u1.s = hi.y;
  lo.x = f2h(s0 - (float)u0.h); lo.y = f2h(s1 - (float)u1.h);
  *reinterpret_cast<ushort2*>(o + (size_t)d * 256 + lane * 2) = hi;
  *reinterpret_cast<ushort2*>(o + (size_t)d * 256 + FIN + lane * 2) = lo;
}

// ---------------- GEMM params + body (R12 staging, single inline site) ----------------
// mode 0: C = acc + bias. mode 1 (fused r/u): v = acc + (Cacc ? Cacc_row : bias);
// cols<256 -> rh=sigmoid(v)*h; 256..511 -> C=sigmoid(v); >=512 -> C=v.
// mode 2: nh = u*h + (1-u)*tanh(xw_c + acc) -> h (+hf mirror).
// A-panel sources MUST be padded to 20096 rows; epilogue masks m<M.
struct GemmP {
  const _Float16* Aa; int lda_a, wrapA, lenA;
  const _Float16* Ab; int lda_b, wrapB;
  const _Float16* B; int ldb;
  float* C; int ldc;
  const float* bias;
  const float* Cacc;
  int M, K, mode;
  float* h; _Float16* hf; float* rh;
  int nch, rpg;
};

static __device__ __forceinline__ void gemm_body(int p, const GemmP& g,
                                                 _Float16* As, _Float16* Bs) {
  int xcd = p & 7;
  int q = p >> 3;
  int rowt = xcd * g.rpg + q / g.nch;
  int chunk = q % g.nch;
  int m0 = rowt * 128;
  if (m0 >= g.M) return;
  int n0 = chunk * 128;

  int tid = threadIdx.x;
  int wave = tid >> 6;
  int lane = tid & 63;
  int wm = wave >> 1, wn = wave & 1;
  int lrow = lane & 15;
  int kgrp = lane >> 4;

  f32x4 acc[4][4] = {};

  // staging: linear LDS write (base + lane*16); XOR swizzle pre-applied to GLOBAL col
  int row8 = lane >> 3;
  int swz8 = 8 * ((lane & 7) ^ row8);
  int wrow = wave * 32;

  for (int k0 = 0; k0 < g.K; k0 += 64) {
    const _Float16* Abase;
    int ka, ldA;
    if (k0 < g.lenA) {
      ka = (k0 >= g.wrapA) ? k0 - g.wrapA : k0;
      Abase = g.Aa; ldA = g.lda_a;
    } else {
      int kp = k0 - g.lenA;
      ka = (kp >= g.wrapB) ? kp - g.wrapB : kp;
      Abase = g.Ab; ldA = g.lda_b;
    }
    __syncthreads();
#pragma unroll
    for (int p4 = 0; p4 < 4; ++p4) {
      int r = wrow + p4 * 8;
      gload_lds16(&Abase[(size_t)(m0 + r + row8) * ldA + ka + swz8], &As[r * 64]);
      gload_lds16(&g.B[(size_t)(n0 + r + row8) * g.ldb + k0 + swz8], &Bs[r * 64]);
    }
    __syncthreads();

#pragma unroll
    for (int kk = 0; kk < 2; ++kk) {
      f16x8 af[4], bf[4];
      int kbyte = kk * 64 + kgrp * 16;
#pragma unroll
      for (int i = 0; i < 4; ++i) {
        int ar = wm * 64 + i * 16 + lrow;
        af[i] = *reinterpret_cast<const f16x8*>(
            reinterpret_cast<const char*>(As) + ar * 128 + (kbyte ^ ((ar & 7) << 4)));
        int br = wn * 64 + i * 16 + lrow;
        bf[i] = *reinterpret_cast<const f16x8*>(
            reinterpret_cast<const char*>(Bs) + br * 128 + (kbyte ^ ((br & 7) << 4)));
      }
#pragma unroll
      for (int i = 0; i < 4; ++i)
#pragma unroll
        for (int j = 0; j < 4; ++j)
          acc[i][j] = __builtin_amdgcn_mfma_f32_16x16x32_f16(bf[j], af[i], acc[i][j], 0, 0, 0);
    }
  }

#pragma unroll
  for (int i = 0; i < 4; ++i) {
    int m = m0 + wm * 64 + i * 16 + lrow;
    if (m >= g.M) continue;
#pragma unroll
    for (int j = 0; j < 4; ++j) {
      int colbase = n0 + wn * 64 + j * 16 + kgrp * 4;
      f32x4 v = acc[i][j];
      if (g.mode == 0) {
        float4 bv4 = *reinterpret_cast<const float4*>(&g.bias[colbase]);
        v[0] += bv4.x; v[1] += bv4.y; v[2] += bv4.z; v[3] += bv4.w;
        *reinterpret_cast<f32x4*>(&g.C[(size_t)m * g.ldc + colbase]) = v;
      } else if (g.mode == 1) {
        if (g.Cacc) {
          float4 a4 = *reinterpret_cast<const float4*>(&g.Cacc[(size_t)m * g.ldc + colbase]);
          v[0] += a4.x; v[1] += a4.y; v[2] += a4.z; v[3] += a4.w;
        } else {
          float4 bv4 = *reinterpret_cast<const float4*>(&g.bias[colbase]);
          v[0] += bv4.x; v[1] += bv4.y; v[2] += bv4.z; v[3] += bv4.w;
        }
        if (colbase < 256) {
          float4 hv = *reinterpret_cast<const float4*>(&g.h[(size_t)m * 256 + colbase]);
          f32x4 rv;
          rv[0] = sigmoidf_(v[0]) * hv.x;
          rv[1] = sigmoidf_(v[1]) * hv.y;
          rv[2] = sigmoidf_(v[2]) * hv.z;
          rv[3] = sigmoidf_(v[3]) * hv.w;
          *reinterpret_cast<f32x4*>(&g.rh[(size_t)m * 256 + colbase]) = rv;
        } else if (colbase < 512) {
          v[0] = sigmoidf_(v[0]); v[1] = sigmoidf_(v[1]);
          v[2] = sigmoidf_(v[2]); v[3] = sigmoidf_(v[3]);
          *reinterpret_cast<f32x4*>(&g.C[(size_t)m * g.ldc + colbase]) = v;
        } else {
          *reinterpret_cast<f32x4*>(&g.C[(size_t)m * g.ldc + colbase]) = v;
        }
      } else {
        float4 xc = *reinterpret_cast<const float4*>(&g.C[(size_t)m * g.ldc + 512 + colbase]);
        float4 uu = *reinterpret_cast<const float4*>(&g.C[(size_t)m * g.ldc + 256 + colbase]);
        float* hp = &g.h[(size_t)m * 256 + colbase];
        float4 hv = *reinterpret_cast<const float4*>(hp);
        float4 nh;
        nh.x = uu.x * hv.x + (1.f - uu.x) * tanhf_(xc.x + v[0]);
        nh.y = uu.y * hv.y + (1.f - uu.y) * tanhf_(xc.y + v[1]);
        nh.z = uu.z * hv.z + (1.f - uu.z) * tanhf_(xc.z + v[2]);
        nh.w = uu.w * hv.w + (1.f - uu.w) * tanhf_(xc.w + v[3]);
        *reinterpret_cast<float4*>(hp) = nh;
        if (g.hf) {
          ushort4 hv16;
          hv16.x = f2h(nh.x); hv16.y = f2h(nh.y);
          hv16.z = f2h(nh.z); hv16.w = f2h(nh.w);
          *reinterpret_cast<ushort4*>(&g.hf[(size_t)m * 256 + colbase]) = hv16;
        }
      }
    }
  }
}

// combo: up to 3 GEMMs per launch. SINGLE gemm_body inline site (R11 lesson).
__global__ __launch_bounds__(256) void combo(GemmP ga, int na, GemmP gb, int nb, GemmP gc) {
  __shared__ _Float16 As[128 * 64];
  __shared__ _Float16 Bs[128 * 64];
  int b = blockIdx.x;
  int sel = (b < na) ? 0 : ((b < na + nb) ? 1 : 2);
  int idx = b - ((sel > 0) ? na : 0) - ((sel > 1) ? nb : 0);
  GemmP g = (sel == 0) ? ga : ((sel == 1) ? gb : gc);
  gemm_body(idx, g, As, Bs);
}

// ---------------- weight prep ----------------
__global__ void wtrans(const float* __restrict__ W, _Float16* __restrict__ dst,
                       int K, int ldw, int ldd, int koff, int mode) {
  int k = blockIdx.x * blockDim.x + threadIdx.x;
  int n = blockIdx.y;
  if (k < K) {
    float w = W[(size_t)k * ldw + n];
    _Float16 hi = (_Float16)w;
    dst[(size_t)n * ldd + koff + k] = mode ? (_Float16)(w - (float)hi) : hi;
  }
}

__global__ void bias_comb(const float* __restrict__ bx, const float* __restrict__ bh,
                          float* __restrict__ out) {
  int i = blockIdx.x * blockDim.x + threadIdx.x;
  if (i < 768) out[i] = bx[i] + bh[i];
}

__global__ void copy_kernel(const float* __restrict__ in, float* __restrict__ out, int n4) {
  int i = blockIdx.x * blockDim.x + threadIdx.x;
  if (i < n4) reinterpret_cast<float4*>(out)[i] = reinterpret_cast<const float4*>(in)[i];
}

// ---------------- host ----------------
extern "C" void kernel_launch(void* const* d_in, const int* in_sizes, int n_in,
                              void* d_out, int out_size, void* d_ws, size_t ws_size,
                              hipStream_t stream) {
  const float* x   = (const float*)d_in[0];
  const float* h0  = (const float*)d_in[1];
  const int*   src = (const int*)d_in[2];
  const int*   dst = (const int*)d_in[3];
  const float* Wx0 = (const float*)d_in[4];
  const float* bx0 = (const float*)d_in[5];
  const float* Wh0 = (const float*)d_in[6];
  const float* bh0 = (const float*)d_in[7];
  const float* Wx1 = (const float*)d_in[8];
  const float* bx1 = (const float*)d_in[9];
  const float* Wh1 = (const float*)d_in[10];
  const float* bh1 = (const float*)d_in[11];
  const float* Wo  = (const float*)d_in[12];
  const float* bo  = (const float*)d_in[13];
  float* out = (float*)d_out;

  char* p = (char*)d_ws;
  auto alloc = [&](size_t bytes) {
    char* r = p;
    p += (bytes + 255) & ~(size_t)255;
    return r;
  };
  int* offs   = (int*)alloc((NN + 1) * sizeof(int));
  int* cursor = (int*)alloc(NN * sizeof(int));
  int* counts = (int*)alloc(NN * sizeof(int));
  int* esrc   = (int*)alloc(NE * sizeof(int));
  _Float16* B0  = (_Float16*)alloc((size_t)768 * 1152 * 2);
  _Float16* B0h = (_Float16*)alloc((size_t)256 * 768 * 2);
  _Float16* B1  = (_Float16*)alloc((size_t)768 * 1536 * 2);
  _Float16* B1h = (_Float16*)alloc((size_t)256 * 768 * 2);
  _Float16* Bo  = (_Float16*)alloc((size_t)128 * 256 * 2);
  float* b0c  = (float*)alloc(768 * 4);
  float* b1c  = (float*)alloc(768 * 4);
  _Float16* XAGG  = (_Float16*)alloc(((size_t)T_STEPS * NN + PADR) * 256 * 2);
  _Float16* H0AGG = (_Float16*)alloc((size_t)(NN + PADR) * 512 * 2);
  _Float16* H1AGG = (_Float16*)alloc((size_t)(NN + PADR) * 512 * 2);
  _Float16* RHAGG = (_Float16*)alloc((size_t)(NN + PADR) * 512 * 2);
  _Float16* h1f   = (_Float16*)alloc((size_t)(NN + PADR) * 256 * 2);
  float* rhf  = (float*)alloc((size_t)NN * 256 * 4);
  float* xw0  = (float*)alloc((size_t)NN * 768 * 4);
  float* xw1  = (float*)alloc((size_t)NN * 768 * 4);

  float* h0c = out + (size_t)T_STEPS * NN * FOUT;
  float* h1c = h0c + (size_t)NN * HD;

  // CSR
  hipMemsetAsync(counts, 0, NN * sizeof(int), stream);
  count_kernel<<<(NE + 255) / 256, 256, 0, stream>>>(dst, counts);
  scan_kernel<<<1, 1024, 0, stream>>>(counts, offs, cursor);
  fill_kernel<<<(NE + 255) / 256, 256, 0, stream>>>(src, dst, cursor, esrc);

  // weight prep (c-gate rows keep all-zero h-part; c h-term via B0h/B1h GEMM)
  hipMemsetAsync(B0, 0, (size_t)768 * 1152 * 2, stream);
  hipMemsetAsync(B1, 0, (size_t)768 * 1536 * 2, stream);
  for (int g = 0; g < 3; ++g) {
    const float* W = Wx0 + (size_t)g * 128 * 256;
    _Float16* D = B0 + (size_t)g * 256 * 1152;
    wtrans<<<dim3(1, 256), 256, 0, stream>>>(W, D, 128, 256, 1152, 0, 0);
    wtrans<<<dim3(1, 256), 256, 0, stream>>>(W, D, 128, 256, 1152, 128, 0);
    wtrans<<<dim3(1, 256), 256, 0, stream>>>(W, D, 128, 256, 1152, 256, 1);
  }
  for (int g = 0; g < 2; ++g) {
    const float* W = Wh0 + (size_t)g * 256 * 256;
    _Float16* D = B0 + (size_t)g * 256 * 1152;
    wtrans<<<dim3(1, 256), 256, 0, stream>>>(W, D, 256, 256, 1152, 384, 0);
    wtrans<<<dim3(1, 256), 256, 0, stream>>>(W, D, 256, 256, 1152, 640, 0);
    wtrans<<<dim3(1, 256), 256, 0, stream>>>(W, D, 256, 256, 1152, 896, 1);
  }
  {
    const float* W = Wh0 + (size_t)2 * 256 * 256;
    wtrans<<<dim3(1, 256), 256, 0, stream>>>(W, B0h, 256, 256, 768, 0, 0);
    wtrans<<<dim3(1, 256), 256, 0, stream>>>(W, B0h, 256, 256, 768, 256, 0);
    wtrans<<<dim3(1, 256), 256, 0, stream>>>(W, B0h, 256, 256, 768, 512, 1);
  }
  for (int g = 0; g < 3; ++g) {
    const float* W = Wx1 + (size_t)g * 256 * 256;
    _Float16* D = B1 + (size_t)g * 256 * 1536;
    wtrans<<<dim3(1, 256), 256, 0, stream>>>(W, D, 256, 256, 1536, 0, 0);
    wtrans<<<dim3(1, 256), 256, 0, stream>>>(W, D, 256, 256, 1536, 256, 0);
    wtrans<<<dim3(1, 256), 256, 0, stream>>>(W, D, 256, 256, 1536, 512, 1);
  }
  for (int g = 0; g < 2; ++g) {
    const float* W = Wh1 + (size_t)g * 256 * 256;
    _Float16* D = B1 + (size_t)g * 256 * 1536;
    wtrans<<<dim3(1, 256), 256, 0, stream>>>(W, D, 256, 256, 1536, 768, 0);
    wtrans<<<dim3(1, 256), 256, 0, stream>>>(W, D, 256, 256, 1536, 1024, 0);
    wtrans<<<dim3(1, 256), 256, 0, stream>>>(W, D, 256, 256, 1536, 1280, 1);
  }
  {
    const float* W = Wh1 + (size_t)2 * 256 * 256;
    wtrans<<<dim3(1, 256), 256, 0, stream>>>(W, B1h, 256, 256, 768, 0, 0);
    wtrans<<<dim3(1, 256), 256, 0, stream>>>(W, B1h, 256, 256, 768, 256, 0);
    wtrans<<<dim3(1, 256), 256, 0, stream>>>(W, B1h, 256, 256, 768, 512, 1);
  }
  wtrans<<<dim3(1, 128), 256, 0, stream>>>(Wo, Bo, 256, 128, 256, 0, 0);
  bias_comb<<<3, 256, 0, stream>>>(bx0, bh0, b0c);
  bias_comb<<<3, 256, 0, stream>>>(bx1, bh1, b1c);

  copy_kernel<<<(2 * NN * HD / 4 + 255) / 256, 256, 0, stream>>>(h0, h0c, 2 * NN * HD / 4);

  dim3 blk(256);
  const int RPG = 20;
  int g6 = 8 * RPG * 6, g2 = 8 * RPG * 2, g1 = 8 * RPG * 1;
  int agg_grid = NN / 4;

  agg_split_x<<<dim3(agg_grid, T_STEPS), blk, 0, stream>>>(x, offs, esrc, XAGG);
  agg_split_h<<<agg_grid, blk, 0, stream>>>(h0c, offs, esrc, H0AGG);

  GemmP dummy = {};
  dummy.nch = 1; dummy.rpg = 1;  // M=0 -> early return

  for (int t = 0; t < T_STEPS; ++t) {
    // ---- A: C1_{t-1} (deferred, RHAGG from F of t-1) ∥ L0_t ----
    GemmP C1p = {RHAGG, 512, 512, 768, nullptr, 0, 0, B1h, 768, xw1, 768, nullptr, nullptr,
                 NN, 768, 2, h1c, h1f, nullptr, 2, RPG};
    GemmP L0p = {XAGG + (size_t)t * NN * 256, 256, 256, 384, H0AGG, 512, 512,
                 B0, 1152, xw0, 768, b0c, nullptr, NN, 1152, 1, h0c, nullptr, rhf, 6, RPG};
    if (t == 0)
      combo<<<g6, blk, 0, stream>>>(L0p, g6, dummy, 0, dummy);
    else
      combo<<<g2 + g6, blk, 0, stream>>>(C1p, g2, L0p, g6, dummy);

    // ---- B: agg(rhf→RHAGG) ∥ agg(h1c→H1AGG) ----
    agg_dual<<<dim3(agg_grid, 2), blk, 0, stream>>>(rhf, RHAGG, h1c, H1AGG, offs, esrc);

    // ---- C: C0_t ∥ L1a_t (H1AGG×Wh1 + b1c → xw1) ----
    GemmP C0p = {RHAGG, 512, 512, 768, nullptr, 0, 0, B0h, 768, xw0, 768, nullptr, nullptr,
                 NN, 768, 2, h0c, nullptr, nullptr, 2, RPG};
    GemmP L1a = {H1AGG, 512, 512, 768, nullptr, 0, 0, B1 + 768, 1536, xw1, 768, b1c, nullptr,
                 NN, 768, 0, nullptr, nullptr, nullptr, 6, RPG};
    combo<<<g2 + g6, blk, 0, stream>>>(C0p, g2, L1a, g6, dummy);

    // ---- D: agg(h0c→H0AGG)  (feeds L1b_t and L0_{t+1}) ----
    agg_split_h<<<agg_grid, blk, 0, stream>>>(h0c, offs, esrc, H0AGG);

    // ---- E: L1b_t (H0AGG×Wx1, Cacc=xw1, fused r/u) ∥ OP_{t-1} (stage balancing) ----
    GemmP L1b = {H0AGG, 512, 512, 768, nullptr, 0, 0, B1, 1536, xw1, 768, nullptr, xw1,
                 NN, 768, 1, h1c, nullptr, rhf, 6, RPG};
    GemmP OPp = {h1f, 256, 256, 256, nullptr, 0, 0, Bo, 256,
                 out + (size_t)(t > 0 ? t - 1 : 0) * NN * FOUT, FOUT, bo, nullptr,
                 NN, 256, 0, nullptr, nullptr, nullptr, 1, RPG};
    if (t == 0)
      combo<<<g6, blk, 0, stream>>>(L1b, g6, dummy, 0, dummy);
    else
      combo<<<g6 + g1, blk, 0, stream>>>(L1b, g6, OPp, g1, dummy);

    // ---- F: agg(rhf→RHAGG)  (feeds C1_t in next step's A) ----
    agg_split_h<<<agg_grid, blk, 0, stream>>>(rhf, offs, esrc, RHAGG);
  }

  // epilogue: C1_{T-1}, then OP_{T-1}
  GemmP C1f = {RHAGG, 512, 512, 768, nullptr, 0, 0, B1h, 768, xw1, 768, nullptr, nullptr,
               NN, 768, 2, h1c, h1f, nullptr, 2, RPG};
  combo<<<g2, blk, 0, stream>>>(C1f, g2, dummy, 0, dummy);
  GemmP OPl = {h1f, 256, 256, 256, nullptr, 0, 0, Bo, 256,
               out + (size_t)(T_STEPS - 1) * NN * FOUT, FOUT, bo, nullptr,
               NN, 256, 0, nullptr, nullptr, nullptr, 1, RPG};
  combo<<<g1, blk, 0, stream>>>(OPl, g1, dummy, 0, dummy);
}

// Round 15
// 4189.540 us; speedup vs baseline: 1.1858x; 1.1488x over previous
//
#include <hip/hip_runtime.h>
#include <hip/hip_bf16.h>
#include <stdint.h>

#define T_STEPS 12
#define NN 20000
#define NE 320000
#define FIN 128
#define HD 256
#define FOUT 128
#define PADR 96  // pad A-panel buffers to 157*128 = 20096 rows

typedef __attribute__((ext_vector_type(4))) float f32x4;
typedef __attribute__((ext_vector_type(8))) _Float16 f16x8;

static __device__ __forceinline__ float sigmoidf_(float x) {
  return 1.0f / (1.0f + __expf(-x));
}
// fast tanh: 1 - 2/(e^{2x}+1); rel err ~1e-7, saturates correctly
static __device__ __forceinline__ float tanhf_(float x) {
  return 1.0f - 2.0f / (__expf(2.0f * x) + 1.0f);
}
static __device__ __forceinline__ ushort f2h(float f) {
  union { ushort s; _Float16 h; } v; v.h = (_Float16)f; return v.s;
}
static __device__ __forceinline__ float h2f(ushort u) {
  union { ushort s; _Float16 h; } v; v.s = u; return (float)v.h;
}

// async global -> LDS, 16B per lane, LDS dest = wave-uniform base + lane*16
static __device__ __forceinline__ void gload_lds16(const _Float16* g, _Float16* l) {
  auto gp = (const __attribute__((address_space(1))) _Float16*)g;
  auto lp = (__attribute__((address_space(3))) _Float16*)l;
  __builtin_amdgcn_global_load_lds(gp, lp, 16, 0, 0);
}

// ---------------- CSR build ----------------
__global__ void count_kernel(const int* __restrict__ dst, int* __restrict__ counts) {
  int e = blockIdx.x * blockDim.x + threadIdx.x;
  if (e < NE) atomicAdd(&counts[dst[e]], 1);
}

__global__ void scan_kernel(const int* __restrict__ counts, int* __restrict__ offs,
                            int* __restrict__ cursor) {
  __shared__ int sm[1024];
  __shared__ int carry_s;
  if (threadIdx.x == 0) carry_s = 0;
  __syncthreads();
  const int n = NN;
  int nch = (n + 1023) >> 10;
  for (int c = 0; c < nch; ++c) {
    int i = (c << 10) + (int)threadIdx.x;
    int v = (i < n) ? counts[i] : 0;
    sm[threadIdx.x] = v;
    __syncthreads();
    for (int off = 1; off < 1024; off <<= 1) {
      int t = (threadIdx.x >= (unsigned)off) ? sm[threadIdx.x - off] : 0;
      __syncthreads();
      sm[threadIdx.x] += t;
      __syncthreads();
    }
    int incl = sm[threadIdx.x];
    int carry_local = carry_s;
    if (i < n) {
      int excl = carry_local + incl - v;
      offs[i] = excl;
      cursor[i] = excl;
    }
    __syncthreads();
    if (threadIdx.x == 1023) carry_s = carry_local + incl;
    __syncthreads();
  }
  if (threadIdx.x == 0) offs[n] = carry_s;
}

__global__ void fill_kernel(const int* __restrict__ src, const int* __restrict__ dst,
                            int* __restrict__ cursor, int* __restrict__ esrc) {
  int e = blockIdx.x * blockDim.x + threadIdx.x;
  if (e < NE) {
    int d = dst[e];
    int pos = atomicAdd(&cursor[d], 1);
    esrc[pos] = src[e];
  }
}

// ---------------- agg body: fp16 gather-sum (512B rows) -> fp16 hi/lo panel (ld 512) ----
// fp32 accumulation; only the pre-gather fp16 rounding of the source is lossy.
static __device__ __forceinline__ void agg_body256_f16(int blk, const _Float16* __restrict__ feat,
                                                       const int* __restrict__ offs,
                                                       const int* __restrict__ esrc,
                                                       _Float16* __restrict__ out) {
  int d = blk * 4 + (threadIdx.x >> 6);
  int lane = threadIdx.x & 63;
  int beg = offs[d], end = offs[d + 1];
  float a[8][4] = {};
  int e = beg;
  for (; e + 7 < end; e += 8) {
    int s[8];
#pragma unroll
    for (int u = 0; u < 8; ++u) s[u] = __builtin_amdgcn_readfirstlane(esrc[e + u]);
#pragma unroll
    for (int u = 0; u < 8; ++u) {
      ushort4 v = *reinterpret_cast<const ushort4*>(feat + (size_t)s[u] * 256 + lane * 4);
      a[u][0] += h2f(v.x); a[u][1] += h2f(v.y); a[u][2] += h2f(v.z); a[u][3] += h2f(v.w);
    }
  }
  for (; e + 3 < end; e += 4) {
    int s[4];
#pragma unroll
    for (int u = 0; u < 4; ++u) s[u] = __builtin_amdgcn_readfirstlane(esrc[e + u]);
#pragma unroll
    for (int u = 0; u < 4; ++u) {
      ushort4 v = *reinterpret_cast<const ushort4*>(feat + (size_t)s[u] * 256 + lane * 4);
      a[u][0] += h2f(v.x); a[u][1] += h2f(v.y); a[u][2] += h2f(v.z); a[u][3] += h2f(v.w);
    }
  }
  for (; e < end; ++e) {
    int s0 = __builtin_amdgcn_readfirstlane(esrc[e]);
    ushort4 v = *reinterpret_cast<const ushort4*>(feat + (size_t)s0 * 256 + lane * 4);
    a[0][0] += h2f(v.x); a[0][1] += h2f(v.y); a[0][2] += h2f(v.z); a[0][3] += h2f(v.w);
  }
  ushort hi[4], lo[4];
#pragma unroll
  for (int p = 0; p < 4; ++p) {
    float s = ((a[0][p] + a[1][p]) + (a[2][p] + a[3][p])) +
              ((a[4][p] + a[5][p]) + (a[6][p] + a[7][p]));
    hi[p] = f2h(s);
    union { ushort us; _Float16 h; } u; u.us = hi[p];
    lo[p] = f2h(s - (float)u.h);
  }
  *reinterpret_cast<ushort4*>(out + (size_t)d * 512 + lane * 4) = *reinterpret_cast<ushort4*>(hi);
  *reinterpret_cast<ushort4*>(out + (size_t)d * 512 + 256 + lane * 4) = *reinterpret_cast<ushort4*>(lo);
}

__global__ void agg_h16(const _Float16* __restrict__ feat, const int* __restrict__ offs,
                        const int* __restrict__ esrc, _Float16* __restrict__ out) {
  agg_body256_f16(blockIdx.x, feat, offs, esrc, out);
}

// dual agg (fp16 sources): two independent gathers in one launch
__global__ void agg_dual16(const _Float16* __restrict__ f0, _Float16* __restrict__ o0,
                           const _Float16* __restrict__ f1, _Float16* __restrict__ o1,
                           const int* __restrict__ offs, const int* __restrict__ esrc) {
  if (blockIdx.y == 0) agg_body256_f16(blockIdx.x, f0, offs, esrc, o0);
  else                 agg_body256_f16(blockIdx.x, f1, offs, esrc, o1);
}

// batched x-aggregation over all T steps (fp32 source, EXACT hi/lo): grid (NN/4, T)
__global__ void agg_split_x(const float* __restrict__ x, const int* __restrict__ offs,
                            const int* __restrict__ esrc, _Float16* __restrict__ out) {
  int t = blockIdx.y;
  const float* feat = x + (size_t)t * NN * FIN;
  _Float16* o = out + (size_t)t * NN * 256;
  int d = blockIdx.x * 4 + (threadIdx.x >> 6);
  int lane = threadIdx.x & 63;
  int beg = offs[d], end = offs[d + 1];
  float a[8][2] = {};
  int e = beg;
  for (; e + 7 < end; e += 8) {
    int s[8];
#pragma unroll
    for (int u = 0; u < 8; ++u) s[u] = __builtin_amdgcn_readfirstlane(esrc[e + u]);
#pragma unroll
    for (int u = 0; u < 8; ++u) {
      float2 v = *reinterpret_cast<const float2*>(feat + (size_t)s[u] * FIN + lane * 2);
      a[u][0] += v.x; a[u][1] += v.y;
    }
  }
  for (; e + 3 < end; e += 4) {
    int s[4];
#pragma unroll
    for (int u = 0; u < 4; ++u) s[u] = __builtin_amdgcn_readfirstlane(esrc[e + u]);
#pragma unroll
    for (int u = 0; u < 4; ++u) {
      float2 v = *reinterpret_cast<const float2*>(feat + (size_t)s[u] * FIN + lane * 2);
      a[u][0] += v.x; a[u][1] += v.y;
    }
  }
  for (; e < end; ++e) {
    int s0 = __builtin_amdgcn_readfirstlane(esrc[e]);
    float2 v = *reinterpret_cast<const float2*>(feat + (size_t)s0 * FIN + lane * 2);
    a[0][0] += v.x; a[0][1] += v.y;
  }
  float s0 = ((a[0][0] + a[1][0]) + (a[2][0] + a[3][0])) +
             ((a[4][0] + a[5][0]) + (a[6][0] + a[7][0]));
  float s1 = ((a[0][1] + a[1][1]) + (a[2][1] + a[3][1])) +
             ((a[4][1] + a[5][1]) + (a[6][1] + a[7][1]));
  ushort2 hi, lo;
  hi.x = f2h(s0); hi.y = f2h(s1);
  union { ushort s; _Float16 h; } u0, u1;
  u0.s = hi.x; u1.s = hi.y;
  lo.x = f2h(s0 - (float)u0.h); lo.y = f2h(s1 - (float)u1.h);
  *reinterpret_cast<ushort2*>(o + (size_t)d * 256 + lane * 2) = hi;
  *reinterpret_cast<ushort2*>(o + (size_t)d * 256 + FIN + lane * 2) = lo;
}

// ---------------- GEMM params + body (R12 staging, single inline site) ----------------
// mode 0: C = acc + bias. mode 1 (fused r/u): v = acc + (Cacc ? Cacc_row : bias);
// cols<256 -> rh16 = fp16(sigmoid(v)*h); 256..511 -> C=sigmoid(v); >=512 -> C=v.
// mode 2: nh = u*h + (1-u)*tanh(xw_c + acc) -> h fp32 (+hf fp16 mirror).
// A-panel sources MUST be padded to 20096 rows; epilogue masks m<M.
struct GemmP {
  const _Float16* Aa; int lda_a, wrapA, lenA;
  const _Float16* Ab; int lda_b, wrapB;
  const _Float16* B; int ldb;
  float* C; int ldc;
  const float* bias;
  const float* Cacc;
  int M, K, mode;
  float* h; _Float16* hf; _Float16* rh16;
  int nch, rpg;
};

static __device__ __forceinline__ void gemm_body(int p, const GemmP& g,
                                                 _Float16* As, _Float16* Bs) {
  int xcd = p & 7;
  int q = p >> 3;
  int rowt = xcd * g.rpg + q / g.nch;
  int chunk = q % g.nch;
  int m0 = rowt * 128;
  if (m0 >= g.M) return;
  int n0 = chunk * 128;

  int tid = threadIdx.x;
  int wave = tid >> 6;
  int lane = tid & 63;
  int wm = wave >> 1, wn = wave & 1;
  int lrow = lane & 15;
  int kgrp = lane >> 4;

  f32x4 acc[4][4] = {};

  // staging: linear LDS write (base + lane*16); XOR swizzle pre-applied to GLOBAL col
  int row8 = lane >> 3;
  int swz8 = 8 * ((lane & 7) ^ row8);
  int wrow = wave * 32;

  for (int k0 = 0; k0 < g.K; k0 += 64) {
    const _Float16* Abase;
    int ka, ldA;
    if (k0 < g.lenA) {
      ka = (k0 >= g.wrapA) ? k0 - g.wrapA : k0;
      Abase = g.Aa; ldA = g.lda_a;
    } else {
      int kp = k0 - g.lenA;
      ka = (kp >= g.wrapB) ? kp - g.wrapB : kp;
      Abase = g.Ab; ldA = g.lda_b;
    }
    __syncthreads();
#pragma unroll
    for (int p4 = 0; p4 < 4; ++p4) {
      int r = wrow + p4 * 8;
      gload_lds16(&Abase[(size_t)(m0 + r + row8) * ldA + ka + swz8], &As[r * 64]);
      gload_lds16(&g.B[(size_t)(n0 + r + row8) * g.ldb + k0 + swz8], &Bs[r * 64]);
    }
    __syncthreads();

#pragma unroll
    for (int kk = 0; kk < 2; ++kk) {
      f16x8 af[4], bf[4];
      int kbyte = kk * 64 + kgrp * 16;
#pragma unroll
      for (int i = 0; i < 4; ++i) {
        int ar = wm * 64 + i * 16 + lrow;
        af[i] = *reinterpret_cast<const f16x8*>(
            reinterpret_cast<const char*>(As) + ar * 128 + (kbyte ^ ((ar & 7) << 4)));
        int br = wn * 64 + i * 16 + lrow;
        bf[i] = *reinterpret_cast<const f16x8*>(
            reinterpret_cast<const char*>(Bs) + br * 128 + (kbyte ^ ((br & 7) << 4)));
      }
#pragma unroll
      for (int i = 0; i < 4; ++i)
#pragma unroll
        for (int j = 0; j < 4; ++j)
          acc[i][j] = __builtin_amdgcn_mfma_f32_16x16x32_f16(bf[j], af[i], acc[i][j], 0, 0, 0);
    }
  }

#pragma unroll
  for (int i = 0; i < 4; ++i) {
    int m = m0 + wm * 64 + i * 16 + lrow;
    if (m >= g.M) continue;
#pragma unroll
    for (int j = 0; j < 4; ++j) {
      int colbase = n0 + wn * 64 + j * 16 + kgrp * 4;
      f32x4 v = acc[i][j];
      if (g.mode == 0) {
        float4 bv4 = *reinterpret_cast<const float4*>(&g.bias[colbase]);
        v[0] += bv4.x; v[1] += bv4.y; v[2] += bv4.z; v[3] += bv4.w;
        *reinterpret_cast<f32x4*>(&g.C[(size_t)m * g.ldc + colbase]) = v;
      } else if (g.mode == 1) {
        if (g.Cacc) {
          float4 a4 = *reinterpret_cast<const float4*>(&g.Cacc[(size_t)m * g.ldc + colbase]);
          v[0] += a4.x; v[1] += a4.y; v[2] += a4.z; v[3] += a4.w;
        } else {
          float4 bv4 = *reinterpret_cast<const float4*>(&g.bias[colbase]);
          v[0] += bv4.x; v[1] += bv4.y; v[2] += bv4.z; v[3] += bv4.w;
        }
        if (colbase < 256) {
          float4 hv = *reinterpret_cast<const float4*>(&g.h[(size_t)m * 256 + colbase]);
          ushort4 rv;
          rv.x = f2h(sigmoidf_(v[0]) * hv.x);
          rv.y = f2h(sigmoidf_(v[1]) * hv.y);
          rv.z = f2h(sigmoidf_(v[2]) * hv.z);
          rv.w = f2h(sigmoidf_(v[3]) * hv.w);
          *reinterpret_cast<ushort4*>(&g.rh16[(size_t)m * 256 + colbase]) = rv;
        } else if (colbase < 512) {
          v[0] = sigmoidf_(v[0]); v[1] = sigmoidf_(v[1]);
          v[2] = sigmoidf_(v[2]); v[3] = sigmoidf_(v[3]);
          *reinterpret_cast<f32x4*>(&g.C[(size_t)m * g.ldc + colbase]) = v;
        } else {
          *reinterpret_cast<f32x4*>(&g.C[(size_t)m * g.ldc + colbase]) = v;
        }
      } else {
        float4 xc = *reinterpret_cast<const float4*>(&g.C[(size_t)m * g.ldc + 512 + colbase]);
        float4 uu = *reinterpret_cast<const float4*>(&g.C[(size_t)m * g.ldc + 256 + colbase]);
        float* hp = &g.h[(size_t)m * 256 + colbase];
        float4 hv = *reinterpret_cast<const float4*>(hp);
        float4 nh;
        nh.x = uu.x * hv.x + (1.f - uu.x) * tanhf_(xc.x + v[0]);
        nh.y = uu.y * hv.y + (1.f - uu.y) * tanhf_(xc.y + v[1]);
        nh.z = uu.z * hv.z + (1.f - uu.z) * tanhf_(xc.z + v[2]);
        nh.w = uu.w * hv.w + (1.f - uu.w) * tanhf_(xc.w + v[3]);
        *reinterpret_cast<float4*>(hp) = nh;
        if (g.hf) {
          ushort4 hv16;
          hv16.x = f2h(nh.x); hv16.y = f2h(nh.y);
          hv16.z = f2h(nh.z); hv16.w = f2h(nh.w);
          *reinterpret_cast<ushort4*>(&g.hf[(size_t)m * 256 + colbase]) = hv16;
        }
      }
    }
  }
}

// combo: up to 3 GEMMs per launch. SINGLE gemm_body inline site (R11 lesson).
__global__ __launch_bounds__(256) void combo(GemmP ga, int na, GemmP gb, int nb, GemmP gc) {
  __shared__ _Float16 As[128 * 64];
  __shared__ _Float16 Bs[128 * 64];
  int b = blockIdx.x;
  int sel = (b < na) ? 0 : ((b < na + nb) ? 1 : 2);
  int idx = b - ((sel > 0) ? na : 0) - ((sel > 1) ? nb : 0);
  GemmP g = (sel == 0) ? ga : ((sel == 1) ? gb : gc);
  gemm_body(idx, g, As, Bs);
}

// ---------------- weight prep / converts ----------------
__global__ void wtrans(const float* __restrict__ W, _Float16* __restrict__ dst,
                       int K, int ldw, int ldd, int koff, int mode) {
  int k = blockIdx.x * blockDim.x + threadIdx.x;
  int n = blockIdx.y;
  if (k < K) {
    float w = W[(size_t)k * ldw + n];
    _Float16 hi = (_Float16)w;
    dst[(size_t)n * ldd + koff + k] = mode ? (_Float16)(w - (float)hi) : hi;
  }
}

__global__ void bias_comb(const float* __restrict__ bx, const float* __restrict__ bh,
                          float* __restrict__ out) {
  int i = blockIdx.x * blockDim.x + threadIdx.x;
  if (i < 768) out[i] = bx[i] + bh[i];
}

__global__ void copy_kernel(const float* __restrict__ in, float* __restrict__ out, int n4) {
  int i = blockIdx.x * blockDim.x + threadIdx.x;
  if (i < n4) reinterpret_cast<float4*>(out)[i] = reinterpret_cast<const float4*>(in)[i];
}

__global__ void cvt16(const float* __restrict__ in, _Float16* __restrict__ out, int n4) {
  int i = blockIdx.x * blockDim.x + threadIdx.x;
  if (i >= n4) return;
  float4 v = reinterpret_cast<const float4*>(in)[i];
  ushort4 o;
  o.x = f2h(v.x); o.y = f2h(v.y); o.z = f2h(v.z); o.w = f2h(v.w);
  reinterpret_cast<ushort4*>(out)[i] = o;
}

// ---------------- host ----------------
extern "C" void kernel_launch(void* const* d_in, const int* in_sizes, int n_in,
                              void* d_out, int out_size, void* d_ws, size_t ws_size,
                              hipStream_t stream) {
  const float* x   = (const float*)d_in[0];
  const float* h0  = (const float*)d_in[1];
  const int*   src = (const int*)d_in[2];
  const int*   dst = (const int*)d_in[3];
  const float* Wx0 = (const float*)d_in[4];
  const float* bx0 = (const float*)d_in[5];
  const float* Wh0 = (const float*)d_in[6];
  const float* bh0 = (const float*)d_in[7];
  const float* Wx1 = (const float*)d_in[8];
  const float* bx1 = (const float*)d_in[9];
  const float* Wh1 = (const float*)d_in[10];
  const float* bh1 = (const float*)d_in[11];
  const float* Wo  = (const float*)d_in[12];
  const float* bo  = (const float*)d_in[13];
  float* out = (float*)d_out;

  char* p = (char*)d_ws;
  auto alloc = [&](size_t bytes) {
    char* r = p;
    p += (bytes + 255) & ~(size_t)255;
    return r;
  };
  int* offs   = (int*)alloc((NN + 1) * sizeof(int));
  int* cursor = (int*)alloc(NN * sizeof(int));
  int* counts = (int*)alloc(NN * sizeof(int));
  int* esrc   = (int*)alloc(NE * sizeof(int));
  _Float16* B0  = (_Float16*)alloc((size_t)768 * 1152 * 2);
  _Float16* B0h = (_Float16*)alloc((size_t)256 * 768 * 2);
  _Float16* B1  = (_Float16*)alloc((size_t)768 * 1536 * 2);
  _Float16* B1h = (_Float16*)alloc((size_t)256 * 768 * 2);
  _Float16* Bo  = (_Float16*)alloc((size_t)128 * 256 * 2);
  float* b0c  = (float*)alloc(768 * 4);
  float* b1c  = (float*)alloc(768 * 4);
  _Float16* XAGG  = (_Float16*)alloc(((size_t)T_STEPS * NN + PADR) * 256 * 2);
  _Float16* H0AGG = (_Float16*)alloc((size_t)(NN + PADR) * 512 * 2);
  _Float16* H1AGG = (_Float16*)alloc((size_t)(NN + PADR) * 512 * 2);
  _Float16* RHAGG = (_Float16*)alloc((size_t)(NN + PADR) * 512 * 2);
  _Float16* h0f   = (_Float16*)alloc((size_t)(NN + PADR) * 256 * 2);  // fp16 gather mirror
  _Float16* h1f   = (_Float16*)alloc((size_t)(NN + PADR) * 256 * 2);  // mirror + OP A-panel
  _Float16* rhf16 = (_Float16*)alloc((size_t)(NN + PADR) * 256 * 2);  // fp16 rh
  float* xw0  = (float*)alloc((size_t)NN * 768 * 4);
  float* xw1  = (float*)alloc((size_t)NN * 768 * 4);

  float* h0c = out + (size_t)T_STEPS * NN * FOUT;
  float* h1c = h0c + (size_t)NN * HD;

  // CSR
  hipMemsetAsync(counts, 0, NN * sizeof(int), stream);
  count_kernel<<<(NE + 255) / 256, 256, 0, stream>>>(dst, counts);
  scan_kernel<<<1, 1024, 0, stream>>>(counts, offs, cursor);
  fill_kernel<<<(NE + 255) / 256, 256, 0, stream>>>(src, dst, cursor, esrc);

  // weight prep (c-gate rows keep all-zero h-part; c h-term via B0h/B1h GEMM)
  hipMemsetAsync(B0, 0, (size_t)768 * 1152 * 2, stream);
  hipMemsetAsync(B1, 0, (size_t)768 * 1536 * 2, stream);
  for (int g = 0; g < 3; ++g) {
    const float* W = Wx0 + (size_t)g * 128 * 256;
    _Float16* D = B0 + (size_t)g * 256 * 1152;
    wtrans<<<dim3(1, 256), 256, 0, stream>>>(W, D, 128, 256, 1152, 0, 0);
    wtrans<<<dim3(1, 256), 256, 0, stream>>>(W, D, 128, 256, 1152, 128, 0);
    wtrans<<<dim3(1, 256), 256, 0, stream>>>(W, D, 128, 256, 1152, 256, 1);
  }
  for (int g = 0; g < 2; ++g) {
    const float* W = Wh0 + (size_t)g * 256 * 256;
    _Float16* D = B0 + (size_t)g * 256 * 1152;
    wtrans<<<dim3(1, 256), 256, 0, stream>>>(W, D, 256, 256, 1152, 384, 0);
    wtrans<<<dim3(1, 256), 256, 0, stream>>>(W, D, 256, 256, 1152, 640, 0);
    wtrans<<<dim3(1, 256), 256, 0, stream>>>(W, D, 256, 256, 1152, 896, 1);
  }
  {
    const float* W = Wh0 + (size_t)2 * 256 * 256;
    wtrans<<<dim3(1, 256), 256, 0, stream>>>(W, B0h, 256, 256, 768, 0, 0);
    wtrans<<<dim3(1, 256), 256, 0, stream>>>(W, B0h, 256, 256, 768, 256, 0);
    wtrans<<<dim3(1, 256), 256, 0, stream>>>(W, B0h, 256, 256, 768, 512, 1);
  }
  for (int g = 0; g < 3; ++g) {
    const float* W = Wx1 + (size_t)g * 256 * 256;
    _Float16* D = B1 + (size_t)g * 256 * 1536;
    wtrans<<<dim3(1, 256), 256, 0, stream>>>(W, D, 256, 256, 1536, 0, 0);
    wtrans<<<dim3(1, 256), 256, 0, stream>>>(W, D, 256, 256, 1536, 256, 0);
    wtrans<<<dim3(1, 256), 256, 0, stream>>>(W, D, 256, 256, 1536, 512, 1);
  }
  for (int g = 0; g < 2; ++g) {
    const float* W = Wh1 + (size_t)g * 256 * 256;
    _Float16* D = B1 + (size_t)g * 256 * 1536;
    wtrans<<<dim3(1, 256), 256, 0, stream>>>(W, D, 256, 256, 1536, 768, 0);
    wtrans<<<dim3(1, 256), 256, 0, stream>>>(W, D, 256, 256, 1536, 1024, 0);
    wtrans<<<dim3(1, 256), 256, 0, stream>>>(W, D, 256, 256, 1536, 1280, 1);
  }
  {
    const float* W = Wh1 + (size_t)2 * 256 * 256;
    wtrans<<<dim3(1, 256), 256, 0, stream>>>(W, B1h, 256, 256, 768, 0, 0);
    wtrans<<<dim3(1, 256), 256, 0, stream>>>(W, B1h, 256, 256, 768, 256, 0);
    wtrans<<<dim3(1, 256), 256, 0, stream>>>(W, B1h, 256, 256, 768, 512, 1);
  }
  wtrans<<<dim3(1, 128), 256, 0, stream>>>(Wo, Bo, 256, 128, 256, 0, 0);
  bias_comb<<<3, 256, 0, stream>>>(bx0, bh0, b0c);
  bias_comb<<<3, 256, 0, stream>>>(bx1, bh1, b1c);

  // init: fp32 states in out tail + fp16 gather mirrors
  copy_kernel<<<(2 * NN * HD / 4 + 255) / 256, 256, 0, stream>>>(h0, h0c, 2 * NN * HD / 4);
  cvt16<<<(NN * HD / 4 + 255) / 256, 256, 0, stream>>>(h0, h0f, NN * HD / 4);
  cvt16<<<(NN * HD / 4 + 255) / 256, 256, 0, stream>>>(h0 + (size_t)NN * HD, h1f, NN * HD / 4);

  dim3 blk(256);
  const int RPG = 20;
  int g6 = 8 * RPG * 6, g2 = 8 * RPG * 2, g1 = 8 * RPG * 1;
  int agg_grid = NN / 4;

  agg_split_x<<<dim3(agg_grid, T_STEPS), blk, 0, stream>>>(x, offs, esrc, XAGG);
  agg_h16<<<agg_grid, blk, 0, stream>>>(h0f, offs, esrc, H0AGG);

  GemmP dummy = {};
  dummy.nch = 1; dummy.rpg = 1;  // M=0 -> early return

  for (int t = 0; t < T_STEPS; ++t) {
    // ---- A: C1_{t-1} (deferred, RHAGG from F of t-1) ∥ L0_t ----
    GemmP C1p = {RHAGG, 512, 512, 768, nullptr, 0, 0, B1h, 768, xw1, 768, nullptr, nullptr,
                 NN, 768, 2, h1c, h1f, nullptr, 2, RPG};
    GemmP L0p = {XAGG + (size_t)t * NN * 256, 256, 256, 384, H0AGG, 512, 512,
                 B0, 1152, xw0, 768, b0c, nullptr, NN, 1152, 1, h0c, nullptr, rhf16, 6, RPG};
    if (t == 0)
      combo<<<g6, blk, 0, stream>>>(L0p, g6, dummy, 0, dummy);
    else
      combo<<<g2 + g6, blk, 0, stream>>>(C1p, g2, L0p, g6, dummy);

    // ---- B: agg(rhf16→RHAGG) ∥ agg(h1f→H1AGG) ----
    agg_dual16<<<dim3(agg_grid, 2), blk, 0, stream>>>(rhf16, RHAGG, h1f, H1AGG, offs, esrc);

    // ---- C: C0_t (writes h0c + h0f mirror) ∥ L1a_t (H1AGG×Wh1 + b1c → xw1) ----
    GemmP C0p = {RHAGG, 512, 512, 768, nullptr, 0, 0, B0h, 768, xw0, 768, nullptr, nullptr,
                 NN, 768, 2, h0c, h0f, nullptr, 2, RPG};
    GemmP L1a = {H1AGG, 512, 512, 768, nullptr, 0, 0, B1 + 768, 1536, xw1, 768, b1c, nullptr,
                 NN, 768, 0, nullptr, nullptr, nullptr, 6, RPG};
    combo<<<g2 + g6, blk, 0, stream>>>(C0p, g2, L1a, g6, dummy);

    // ---- D: agg(h0f→H0AGG)  (feeds L1b_t and L0_{t+1}) ----
    agg_h16<<<agg_grid, blk, 0, stream>>>(h0f, offs, esrc, H0AGG);

    // ---- E: L1b_t (H0AGG×Wx1, Cacc=xw1, fused r/u) ∥ OP_{t-1} ----
    GemmP L1b = {H0AGG, 512, 512, 768, nullptr, 0, 0, B1, 1536, xw1, 768, nullptr, xw1,
                 NN, 768, 1, h1c, nullptr, rhf16, 6, RPG};
    GemmP OPp = {h1f, 256, 256, 256, nullptr, 0, 0, Bo, 256,
                 out + (size_t)(t > 0 ? t - 1 : 0) * NN * FOUT, FOUT, bo, nullptr,
                 NN, 256, 0, nullptr, nullptr, nullptr, 1, RPG};
    if (t == 0)
      combo<<<g6, blk, 0, stream>>>(L1b, g6, dummy, 0, dummy);
    else
      combo<<<g6 + g1, blk, 0, stream>>>(L1b, g6, OPp, g1, dummy);

    // ---- F: agg(rhf16→RHAGG)  (feeds C1_t in next step's A) ----
    agg_h16<<<agg_grid, blk, 0, stream>>>(rhf16, offs, esrc, RHAGG);
  }

  // epilogue: C1_{T-1}, then OP_{T-1}
  GemmP C1f = {RHAGG, 512, 512, 768, nullptr, 0, 0, B1h, 768, xw1, 768, nullptr, nullptr,
               NN, 768, 2, h1c, h1f, nullptr, 2, RPG};
  combo<<<g2, blk, 0, stream>>>(C1f, g2, dummy, 0, dummy);
  GemmP OPl = {h1f, 256, 256, 256, nullptr, 0, 0, Bo, 256,
               out + (size_t)(T_STEPS - 1) * NN * FOUT, FOUT, bo, nullptr,
               NN, 256, 0, nullptr, nullptr, nullptr, 1, RPG};
  combo<<<g1, blk, 0, stream>>>(OPl, g1, dummy, 0, dummy);
}

// Round 16
// 3986.383 us; speedup vs baseline: 1.2463x; 1.0510x over previous
//
#include <hip/hip_runtime.h>
#include <hip/hip_bf16.h>
#include <stdint.h>

#define T_STEPS 12
#define NN 20000
#define NE 320000
#define FIN 128
#define HD 256
#define FOUT 128
#define PADR 96  // pad A-panel buffers to 157*128 = 20096 rows

typedef __attribute__((ext_vector_type(4))) float f32x4;
typedef __attribute__((ext_vector_type(8))) _Float16 f16x8;

static __device__ __forceinline__ float sigmoidf_(float x) {
  return 1.0f / (1.0f + __expf(-x));
}
// fast tanh: 1 - 2/(e^{2x}+1); rel err ~1e-7, saturates correctly
static __device__ __forceinline__ float tanhf_(float x) {
  return 1.0f - 2.0f / (__expf(2.0f * x) + 1.0f);
}
static __device__ __forceinline__ ushort f2h(float f) {
  union { ushort s; _Float16 h; } v; v.h = (_Float16)f; return v.s;
}
static __device__ __forceinline__ float h2f(ushort u) {
  union { ushort s; _Float16 h; } v; v.s = u; return (float)v.h;
}

// async global -> LDS, 16B per lane, LDS dest = wave-uniform base + lane*16
static __device__ __forceinline__ void gload_lds16(const _Float16* g, _Float16* l) {
  auto gp = (const __attribute__((address_space(1))) _Float16*)g;
  auto lp = (__attribute__((address_space(3))) _Float16*)l;
  __builtin_amdgcn_global_load_lds(gp, lp, 16, 0, 0);
}

// ---------------- CSR build ----------------
__global__ void count_kernel(const int* __restrict__ dst, int* __restrict__ counts) {
  int e = blockIdx.x * blockDim.x + threadIdx.x;
  if (e < NE) atomicAdd(&counts[dst[e]], 1);
}

__global__ void scan_kernel(const int* __restrict__ counts, int* __restrict__ offs,
                            int* __restrict__ cursor) {
  __shared__ int sm[1024];
  __shared__ int carry_s;
  if (threadIdx.x == 0) carry_s = 0;
  __syncthreads();
  const int n = NN;
  int nch = (n + 1023) >> 10;
  for (int c = 0; c < nch; ++c) {
    int i = (c << 10) + (int)threadIdx.x;
    int v = (i < n) ? counts[i] : 0;
    sm[threadIdx.x] = v;
    __syncthreads();
    for (int off = 1; off < 1024; off <<= 1) {
      int t = (threadIdx.x >= (unsigned)off) ? sm[threadIdx.x - off] : 0;
      __syncthreads();
      sm[threadIdx.x] += t;
      __syncthreads();
    }
    int incl = sm[threadIdx.x];
    int carry_local = carry_s;
    if (i < n) {
      int excl = carry_local + incl - v;
      offs[i] = excl;
      cursor[i] = excl;
    }
    __syncthreads();
    if (threadIdx.x == 1023) carry_s = carry_local + incl;
    __syncthreads();
  }
  if (threadIdx.x == 0) offs[n] = carry_s;
}

__global__ void fill_kernel(const int* __restrict__ src, const int* __restrict__ dst,
                            int* __restrict__ cursor, int* __restrict__ esrc) {
  int e = blockIdx.x * blockDim.x + threadIdx.x;
  if (e < NE) {
    int d = dst[e];
    int pos = atomicAdd(&cursor[d], 1);
    esrc[pos] = src[e];
  }
}

// ---------------- agg body: fp16 gather-sum (512B rows) -> fp16 hi/lo panel (ld 512) ----
static __device__ __forceinline__ void agg_body256_f16(int blk, const _Float16* __restrict__ feat,
                                                       const int* __restrict__ offs,
                                                       const int* __restrict__ esrc,
                                                       _Float16* __restrict__ out) {
  int d = blk * 4 + (threadIdx.x >> 6);
  int lane = threadIdx.x & 63;
  int beg = offs[d], end = offs[d + 1];
  float a[8][4] = {};
  int e = beg;
  for (; e + 7 < end; e += 8) {
    int s[8];
#pragma unroll
    for (int u = 0; u < 8; ++u) s[u] = __builtin_amdgcn_readfirstlane(esrc[e + u]);
#pragma unroll
    for (int u = 0; u < 8; ++u) {
      ushort4 v = *reinterpret_cast<const ushort4*>(feat + (size_t)s[u] * 256 + lane * 4);
      a[u][0] += h2f(v.x); a[u][1] += h2f(v.y); a[u][2] += h2f(v.z); a[u][3] += h2f(v.w);
    }
  }
  for (; e + 3 < end; e += 4) {
    int s[4];
#pragma unroll
    for (int u = 0; u < 4; ++u) s[u] = __builtin_amdgcn_readfirstlane(esrc[e + u]);
#pragma unroll
    for (int u = 0; u < 4; ++u) {
      ushort4 v = *reinterpret_cast<const ushort4*>(feat + (size_t)s[u] * 256 + lane * 4);
      a[u][0] += h2f(v.x); a[u][1] += h2f(v.y); a[u][2] += h2f(v.z); a[u][3] += h2f(v.w);
    }
  }
  for (; e < end; ++e) {
    int s0 = __builtin_amdgcn_readfirstlane(esrc[e]);
    ushort4 v = *reinterpret_cast<const ushort4*>(feat + (size_t)s0 * 256 + lane * 4);
    a[0][0] += h2f(v.x); a[0][1] += h2f(v.y); a[0][2] += h2f(v.z); a[0][3] += h2f(v.w);
  }
  ushort hi[4], lo[4];
#pragma unroll
  for (int p = 0; p < 4; ++p) {
    float s = ((a[0][p] + a[1][p]) + (a[2][p] + a[3][p])) +
              ((a[4][p] + a[5][p]) + (a[6][p] + a[7][p]));
    hi[p] = f2h(s);
    union { ushort us; _Float16 h; } u; u.us = hi[p];
    lo[p] = f2h(s - (float)u.h);
  }
  *reinterpret_cast<ushort4*>(out + (size_t)d * 512 + lane * 4) = *reinterpret_cast<ushort4*>(hi);
  *reinterpret_cast<ushort4*>(out + (size_t)d * 512 + 256 + lane * 4) = *reinterpret_cast<ushort4*>(lo);
}

__global__ void agg_h16(const _Float16* __restrict__ feat, const int* __restrict__ offs,
                        const int* __restrict__ esrc, _Float16* __restrict__ out) {
  agg_body256_f16(blockIdx.x, feat, offs, esrc, out);
}

// dual agg (fp16 sources): two independent gathers in one launch
__global__ void agg_dual16(const _Float16* __restrict__ f0, _Float16* __restrict__ o0,
                           const _Float16* __restrict__ f1, _Float16* __restrict__ o1,
                           const int* __restrict__ offs, const int* __restrict__ esrc) {
  if (blockIdx.y == 0) agg_body256_f16(blockIdx.x, f0, offs, esrc, o0);
  else                 agg_body256_f16(blockIdx.x, f1, offs, esrc, o1);
}

// batched x-aggregation over all T steps, fp16 source (256B rows): grid (NN/4, T)
// out [t][N][256] = [hi128|lo128]; fp32 accumulate, hi/lo split of the aggregate
__global__ void agg_split_x16(const _Float16* __restrict__ xf, const int* __restrict__ offs,
                              const int* __restrict__ esrc, _Float16* __restrict__ out) {
  int t = blockIdx.y;
  const _Float16* feat = xf + (size_t)t * NN * FIN;
  _Float16* o = out + (size_t)t * NN * 256;
  int d = blockIdx.x * 4 + (threadIdx.x >> 6);
  int lane = threadIdx.x & 63;
  int beg = offs[d], end = offs[d + 1];
  float a[8][2] = {};
  int e = beg;
  for (; e + 7 < end; e += 8) {
    int s[8];
#pragma unroll
    for (int u = 0; u < 8; ++u) s[u] = __builtin_amdgcn_readfirstlane(esrc[e + u]);
#pragma unroll
    for (int u = 0; u < 8; ++u) {
      ushort2 v = *reinterpret_cast<const ushort2*>(feat + (size_t)s[u] * FIN + lane * 2);
      a[u][0] += h2f(v.x); a[u][1] += h2f(v.y);
    }
  }
  for (; e + 3 < end; e += 4) {
    int s[4];
#pragma unroll
    for (int u = 0; u < 4; ++u) s[u] = __builtin_amdgcn_readfirstlane(esrc[e + u]);
#pragma unroll
    for (int u = 0; u < 4; ++u) {
      ushort2 v = *reinterpret_cast<const ushort2*>(feat + (size_t)s[u] * FIN + lane * 2);
      a[u][0] += h2f(v.x); a[u][1] += h2f(v.y);
    }
  }
  for (; e < end; ++e) {
    int s0 = __builtin_amdgcn_readfirstlane(esrc[e]);
    ushort2 v = *reinterpret_cast<const ushort2*>(feat + (size_t)s0 * FIN + lane * 2);
    a[0][0] += h2f(v.x); a[0][1] += h2f(v.y);
  }
  float s0 = ((a[0][0] + a[1][0]) + (a[2][0] + a[3][0])) +
             ((a[4][0] + a[5][0]) + (a[6][0] + a[7][0]));
  float s1 = ((a[0][1] + a[1][1]) + (a[2][1] + a[3][1])) +
             ((a[4][1] + a[5][1]) + (a[6][1] + a[7][1]));
  ushort2 hi, lo;
  hi.x = f2h(s0); hi.y = f2h(s1);
  union { ushort s; _Float16 h; } u0, u1;
  u0.s = hi.x; u1.s = hi.y;
  lo.x = f2h(s0 - (float)u0.h); lo.y = f2h(s1 - (float)u1.h);
  *reinterpret_cast<ushort2*>(o + (size_t)d * 256 + lane * 2) = hi;
  *reinterpret_cast<ushort2*>(o + (size_t)d * 256 + FIN + lane * 2) = lo;
}

// ---------------- GEMM params + body (R12 staging, single inline site) ----------------
// mode 0: C = acc + bias. mode 1 (fused r/u): v = acc + (Cacc ? Cacc_row : bias);
// cols<256 -> rh16 = fp16(sigmoid(v)*h); 256..511 -> C=sigmoid(v); >=512 -> C=v.
// mode 2: nh = u*h + (1-u)*tanh(xw_c + acc) -> h fp32 (+hf fp16 mirror).
// A-panel sources MUST be padded to 20096 rows; epilogue masks m<M.
struct GemmP {
  const _Float16* Aa; int lda_a, wrapA, lenA;
  const _Float16* Ab; int lda_b, wrapB;
  const _Float16* B; int ldb;
  float* C; int ldc;
  const float* bias;
  const float* Cacc;
  int M, K, mode;
  float* h; _Float16* hf; _Float16* rh16;
  int nch, rpg;
};

static __device__ __forceinline__ void gemm_body(int p, const GemmP& g,
                                                 _Float16* As, _Float16* Bs) {
  int xcd = p & 7;
  int q = p >> 3;
  int rowt = xcd * g.rpg + q / g.nch;
  int chunk = q % g.nch;
  int m0 = rowt * 128;
  if (m0 >= g.M) return;
  int n0 = chunk * 128;

  int tid = threadIdx.x;
  int wave = tid >> 6;
  int lane = tid & 63;
  int wm = wave >> 1, wn = wave & 1;
  int lrow = lane & 15;
  int kgrp = lane >> 4;

  f32x4 acc[4][4] = {};

  // staging: linear LDS write (base + lane*16); XOR swizzle pre-applied to GLOBAL col
  int row8 = lane >> 3;
  int swz8 = 8 * ((lane & 7) ^ row8);
  int wrow = wave * 32;

  for (int k0 = 0; k0 < g.K; k0 += 64) {
    const _Float16* Abase;
    int ka, ldA;
    if (k0 < g.lenA) {
      ka = (k0 >= g.wrapA) ? k0 - g.wrapA : k0;
      Abase = g.Aa; ldA = g.lda_a;
    } else {
      int kp = k0 - g.lenA;
      ka = (kp >= g.wrapB) ? kp - g.wrapB : kp;
      Abase = g.Ab; ldA = g.lda_b;
    }
    __syncthreads();
#pragma unroll
    for (int p4 = 0; p4 < 4; ++p4) {
      int r = wrow + p4 * 8;
      gload_lds16(&Abase[(size_t)(m0 + r + row8) * ldA + ka + swz8], &As[r * 64]);
      gload_lds16(&g.B[(size_t)(n0 + r + row8) * g.ldb + k0 + swz8], &Bs[r * 64]);
    }
    __syncthreads();

#pragma unroll
    for (int kk = 0; kk < 2; ++kk) {
      f16x8 af[4], bf[4];
      int kbyte = kk * 64 + kgrp * 16;
#pragma unroll
      for (int i = 0; i < 4; ++i) {
        int ar = wm * 64 + i * 16 + lrow;
        af[i] = *reinterpret_cast<const f16x8*>(
            reinterpret_cast<const char*>(As) + ar * 128 + (kbyte ^ ((ar & 7) << 4)));
        int br = wn * 64 + i * 16 + lrow;
        bf[i] = *reinterpret_cast<const f16x8*>(
            reinterpret_cast<const char*>(Bs) + br * 128 + (kbyte ^ ((br & 7) << 4)));
      }
#pragma unroll
      for (int i = 0; i < 4; ++i)
#pragma unroll
        for (int j = 0; j < 4; ++j)
          acc[i][j] = __builtin_amdgcn_mfma_f32_16x16x32_f16(bf[j], af[i], acc[i][j], 0, 0, 0);
    }
  }

#pragma unroll
  for (int i = 0; i < 4; ++i) {
    int m = m0 + wm * 64 + i * 16 + lrow;
    if (m >= g.M) continue;
#pragma unroll
    for (int j = 0; j < 4; ++j) {
      int colbase = n0 + wn * 64 + j * 16 + kgrp * 4;
      f32x4 v = acc[i][j];
      if (g.mode == 0) {
        float4 bv4 = *reinterpret_cast<const float4*>(&g.bias[colbase]);
        v[0] += bv4.x; v[1] += bv4.y; v[2] += bv4.z; v[3] += bv4.w;
        *reinterpret_cast<f32x4*>(&g.C[(size_t)m * g.ldc + colbase]) = v;
      } else if (g.mode == 1) {
        if (g.Cacc) {
          float4 a4 = *reinterpret_cast<const float4*>(&g.Cacc[(size_t)m * g.ldc + colbase]);
          v[0] += a4.x; v[1] += a4.y; v[2] += a4.z; v[3] += a4.w;
        } else {
          float4 bv4 = *reinterpret_cast<const float4*>(&g.bias[colbase]);
          v[0] += bv4.x; v[1] += bv4.y; v[2] += bv4.z; v[3] += bv4.w;
        }
        if (colbase < 256) {
          float4 hv = *reinterpret_cast<const float4*>(&g.h[(size_t)m * 256 + colbase]);
          ushort4 rv;
          rv.x = f2h(sigmoidf_(v[0]) * hv.x);
          rv.y = f2h(sigmoidf_(v[1]) * hv.y);
          rv.z = f2h(sigmoidf_(v[2]) * hv.z);
          rv.w = f2h(sigmoidf_(v[3]) * hv.w);
          *reinterpret_cast<ushort4*>(&g.rh16[(size_t)m * 256 + colbase]) = rv;
        } else if (colbase < 512) {
          v[0] = sigmoidf_(v[0]); v[1] = sigmoidf_(v[1]);
          v[2] = sigmoidf_(v[2]); v[3] = sigmoidf_(v[3]);
          *reinterpret_cast<f32x4*>(&g.C[(size_t)m * g.ldc + colbase]) = v;
        } else {
          *reinterpret_cast<f32x4*>(&g.C[(size_t)m * g.ldc + colbase]) = v;
        }
      } else {
        float4 xc = *reinterpret_cast<const float4*>(&g.C[(size_t)m * g.ldc + 512 + colbase]);
        float4 uu = *reinterpret_cast<const float4*>(&g.C[(size_t)m * g.ldc + 256 + colbase]);
        float* hp = &g.h[(size_t)m * 256 + colbase];
        float4 hv = *reinterpret_cast<const float4*>(hp);
        float4 nh;
        nh.x = uu.x * hv.x + (1.f - uu.x) * tanhf_(xc.x + v[0]);
        nh.y = uu.y * hv.y + (1.f - uu.y) * tanhf_(xc.y + v[1]);
        nh.z = uu.z * hv.z + (1.f - uu.z) * tanhf_(xc.z + v[2]);
        nh.w = uu.w * hv.w + (1.f - uu.w) * tanhf_(xc.w + v[3]);
        *reinterpret_cast<float4*>(hp) = nh;
        if (g.hf) {
          ushort4 hv16;
          hv16.x = f2h(nh.x); hv16.y = f2h(nh.y);
          hv16.z = f2h(nh.z); hv16.w = f2h(nh.w);
          *reinterpret_cast<ushort4*>(&g.hf[(size_t)m * 256 + colbase]) = hv16;
        }
      }
    }
  }
}

// combo: up to 3 GEMMs per launch. SINGLE gemm_body inline site (R11 lesson).
__global__ __launch_bounds__(256) void combo(GemmP ga, int na, GemmP gb, int nb, GemmP gc) {
  __shared__ _Float16 As[128 * 64];
  __shared__ _Float16 Bs[128 * 64];
  int b = blockIdx.x;
  int sel = (b < na) ? 0 : ((b < na + nb) ? 1 : 2);
  int idx = b - ((sel > 0) ? na : 0) - ((sel > 1) ? nb : 0);
  GemmP g = (sel == 0) ? ga : ((sel == 1) ? gb : gc);
  gemm_body(idx, g, As, Bs);
}

// ---------------- weight prep / converts ----------------
__global__ void wtrans(const float* __restrict__ W, _Float16* __restrict__ dst,
                       int K, int ldw, int ldd, int koff, int mode) {
  int k = blockIdx.x * blockDim.x + threadIdx.x;
  int n = blockIdx.y;
  if (k < K) {
    float w = W[(size_t)k * ldw + n];
    _Float16 hi = (_Float16)w;
    dst[(size_t)n * ldd + koff + k] = mode ? (_Float16)(w - (float)hi) : hi;
  }
}

__global__ void bias_comb(const float* __restrict__ bx, const float* __restrict__ bh,
                          float* __restrict__ out) {
  int i = blockIdx.x * blockDim.x + threadIdx.x;
  if (i < 768) out[i] = bx[i] + bh[i];
}

__global__ void copy_kernel(const float* __restrict__ in, float* __restrict__ out, int n4) {
  int i = blockIdx.x * blockDim.x + threadIdx.x;
  if (i < n4) reinterpret_cast<float4*>(out)[i] = reinterpret_cast<const float4*>(in)[i];
}

__global__ void cvt16(const float* __restrict__ in, _Float16* __restrict__ out, int n4) {
  int i = blockIdx.x * blockDim.x + threadIdx.x;
  if (i >= n4) return;
  float4 v = reinterpret_cast<const float4*>(in)[i];
  ushort4 o;
  o.x = f2h(v.x); o.y = f2h(v.y); o.z = f2h(v.z); o.w = f2h(v.w);
  reinterpret_cast<ushort4*>(out)[i] = o;
}

// ---------------- host ----------------
extern "C" void kernel_launch(void* const* d_in, const int* in_sizes, int n_in,
                              void* d_out, int out_size, void* d_ws, size_t ws_size,
                              hipStream_t stream) {
  const float* x   = (const float*)d_in[0];
  const float* h0  = (const float*)d_in[1];
  const int*   src = (const int*)d_in[2];
  const int*   dst = (const int*)d_in[3];
  const float* Wx0 = (const float*)d_in[4];
  const float* bx0 = (const float*)d_in[5];
  const float* Wh0 = (const float*)d_in[6];
  const float* bh0 = (const float*)d_in[7];
  const float* Wx1 = (const float*)d_in[8];
  const float* bx1 = (const float*)d_in[9];
  const float* Wh1 = (const float*)d_in[10];
  const float* bh1 = (const float*)d_in[11];
  const float* Wo  = (const float*)d_in[12];
  const float* bo  = (const float*)d_in[13];
  float* out = (float*)d_out;

  char* p = (char*)d_ws;
  auto alloc = [&](size_t bytes) {
    char* r = p;
    p += (bytes + 255) & ~(size_t)255;
    return r;
  };
  int* offs   = (int*)alloc((NN + 1) * sizeof(int));
  int* cursor = (int*)alloc(NN * sizeof(int));
  int* counts = (int*)alloc(NN * sizeof(int));
  int* esrc   = (int*)alloc(NE * sizeof(int));
  // B0 K-layout (1024): x-part 2-term [Wx_hi@0 | Wx_hi@128]; h-part 3-term
  // [Wh_hi@256 | Wh_hi@512 | Wh_lo@768]. c-gate rows: h-part all-zero.
  _Float16* B0  = (_Float16*)alloc((size_t)768 * 1024 * 2);
  _Float16* B0h = (_Float16*)alloc((size_t)256 * 768 * 2);
  _Float16* B1  = (_Float16*)alloc((size_t)768 * 1536 * 2);
  _Float16* B1h = (_Float16*)alloc((size_t)256 * 768 * 2);
  _Float16* Bo  = (_Float16*)alloc((size_t)128 * 256 * 2);
  float* b0c  = (float*)alloc(768 * 4);
  float* b1c  = (float*)alloc(768 * 4);
  _Float16* xf    = (_Float16*)alloc((size_t)T_STEPS * NN * FIN * 2);  // fp16 x mirror
  _Float16* XAGG  = (_Float16*)alloc(((size_t)T_STEPS * NN + PADR) * 256 * 2);
  _Float16* H0AGG = (_Float16*)alloc((size_t)(NN + PADR) * 512 * 2);
  _Float16* H1AGG = (_Float16*)alloc((size_t)(NN + PADR) * 512 * 2);
  _Float16* RHAGG = (_Float16*)alloc((size_t)(NN + PADR) * 512 * 2);
  _Float16* h0f   = (_Float16*)alloc((size_t)(NN + PADR) * 256 * 2);  // fp16 gather mirror
  _Float16* h1f   = (_Float16*)alloc((size_t)(NN + PADR) * 256 * 2);  // mirror + OP A-panel
  _Float16* rhf16 = (_Float16*)alloc((size_t)(NN + PADR) * 256 * 2);  // fp16 rh
  float* xw0  = (float*)alloc((size_t)NN * 768 * 4);
  float* xw1  = (float*)alloc((size_t)NN * 768 * 4);

  float* h0c = out + (size_t)T_STEPS * NN * FOUT;
  float* h1c = h0c + (size_t)NN * HD;

  // CSR
  hipMemsetAsync(counts, 0, NN * sizeof(int), stream);
  count_kernel<<<(NE + 255) / 256, 256, 0, stream>>>(dst, counts);
  scan_kernel<<<1, 1024, 0, stream>>>(counts, offs, cursor);
  fill_kernel<<<(NE + 255) / 256, 256, 0, stream>>>(src, dst, cursor, esrc);

  // weight prep
  hipMemsetAsync(B0, 0, (size_t)768 * 1024 * 2, stream);
  hipMemsetAsync(B1, 0, (size_t)768 * 1536 * 2, stream);
  for (int g = 0; g < 3; ++g) {
    const float* W = Wx0 + (size_t)g * 128 * 256;
    _Float16* D = B0 + (size_t)g * 256 * 1024;
    wtrans<<<dim3(1, 256), 256, 0, stream>>>(W, D, 128, 256, 1024, 0, 0);
    wtrans<<<dim3(1, 256), 256, 0, stream>>>(W, D, 128, 256, 1024, 128, 0);
  }
  for (int g = 0; g < 2; ++g) {
    const float* W = Wh0 + (size_t)g * 256 * 256;
    _Float16* D = B0 + (size_t)g * 256 * 1024;
    wtrans<<<dim3(1, 256), 256, 0, stream>>>(W, D, 256, 256, 1024, 256, 0);
    wtrans<<<dim3(1, 256), 256, 0, stream>>>(W, D, 256, 256, 1024, 512, 0);
    wtrans<<<dim3(1, 256), 256, 0, stream>>>(W, D, 256, 256, 1024, 768, 1);
  }
  {
    const float* W = Wh0 + (size_t)2 * 256 * 256;
    wtrans<<<dim3(1, 256), 256, 0, stream>>>(W, B0h, 256, 256, 768, 0, 0);
    wtrans<<<dim3(1, 256), 256, 0, stream>>>(W, B0h, 256, 256, 768, 256, 0);
    wtrans<<<dim3(1, 256), 256, 0, stream>>>(W, B0h, 256, 256, 768, 512, 1);
  }
  for (int g = 0; g < 3; ++g) {
    const float* W = Wx1 + (size_t)g * 256 * 256;
    _Float16* D = B1 + (size_t)g * 256 * 1536;
    wtrans<<<dim3(1, 256), 256, 0, stream>>>(W, D, 256, 256, 1536, 0, 0);
    wtrans<<<dim3(1, 256), 256, 0, stream>>>(W, D, 256, 256, 1536, 256, 0);
    wtrans<<<dim3(1, 256), 256, 0, stream>>>(W, D, 256, 256, 1536, 512, 1);
  }
  for (int g = 0; g < 2; ++g) {
    const float* W = Wh1 + (size_t)g * 256 * 256;
    _Float16* D = B1 + (size_t)g * 256 * 1536;
    wtrans<<<dim3(1, 256), 256, 0, stream>>>(W, D, 256, 256, 1536, 768, 0);
    wtrans<<<dim3(1, 256), 256, 0, stream>>>(W, D, 256, 256, 1536, 1024, 0);
    wtrans<<<dim3(1, 256), 256, 0, stream>>>(W, D, 256, 256, 1536, 1280, 1);
  }
  {
    const float* W = Wh1 + (size_t)2 * 256 * 256;
    wtrans<<<dim3(1, 256), 256, 0, stream>>>(W, B1h, 256, 256, 768, 0, 0);
    wtrans<<<dim3(1, 256), 256, 0, stream>>>(W, B1h, 256, 256, 768, 256, 0);
    wtrans<<<dim3(1, 256), 256, 0, stream>>>(W, B1h, 256, 256, 768, 512, 1);
  }
  wtrans<<<dim3(1, 128), 256, 0, stream>>>(Wo, Bo, 256, 128, 256, 0, 0);
  bias_comb<<<3, 256, 0, stream>>>(bx0, bh0, b0c);
  bias_comb<<<3, 256, 0, stream>>>(bx1, bh1, b1c);

  // init: fp32 states in out tail + fp16 mirrors (h and x)
  copy_kernel<<<(2 * NN * HD / 4 + 255) / 256, 256, 0, stream>>>(h0, h0c, 2 * NN * HD / 4);
  cvt16<<<(NN * HD / 4 + 255) / 256, 256, 0, stream>>>(h0, h0f, NN * HD / 4);
  cvt16<<<(NN * HD / 4 + 255) / 256, 256, 0, stream>>>(h0 + (size_t)NN * HD, h1f, NN * HD / 4);
  cvt16<<<(T_STEPS * NN * FIN / 4 + 255) / 256, 256, 0, stream>>>(x, xf, T_STEPS * NN * FIN / 4);

  dim3 blk(256);
  const int RPG = 20;
  int g6 = 8 * RPG * 6, g2 = 8 * RPG * 2, g1 = 8 * RPG * 1;
  int agg_grid = NN / 4;

  agg_split_x16<<<dim3(agg_grid, T_STEPS), blk, 0, stream>>>(xf, offs, esrc, XAGG);
  agg_h16<<<agg_grid, blk, 0, stream>>>(h0f, offs, esrc, H0AGG);

  GemmP dummy = {};
  dummy.nch = 1; dummy.rpg = 1;  // M=0 -> early return

  for (int t = 0; t < T_STEPS; ++t) {
    // ---- A: C1_{t-1} (deferred, RHAGG from F of t-1) ∥ L0_t (K=1024) ----
    GemmP C1p = {RHAGG, 512, 512, 768, nullptr, 0, 0, B1h, 768, xw1, 768, nullptr, nullptr,
                 NN, 768, 2, h1c, h1f, nullptr, 2, RPG};
    GemmP L0p = {XAGG + (size_t)t * NN * 256, 256, 256, 256, H0AGG, 512, 512,
                 B0, 1024, xw0, 768, b0c, nullptr, NN, 1024, 1, h0c, nullptr, rhf16, 6, RPG};
    if (t == 0)
      combo<<<g6, blk, 0, stream>>>(L0p, g6, dummy, 0, dummy);
    else
      combo<<<g2 + g6, blk, 0, stream>>>(C1p, g2, L0p, g6, dummy);

    // ---- B: agg(rhf16→RHAGG) ∥ agg(h1f→H1AGG) ----
    agg_dual16<<<dim3(agg_grid, 2), blk, 0, stream>>>(rhf16, RHAGG, h1f, H1AGG, offs, esrc);

    // ---- C: C0_t (writes h0c + h0f mirror) ∥ L1a_t (H1AGG×Wh1 + b1c → xw1) ----
    GemmP C0p = {RHAGG, 512, 512, 768, nullptr, 0, 0, B0h, 768, xw0, 768, nullptr, nullptr,
                 NN, 768, 2, h0c, h0f, nullptr, 2, RPG};
    GemmP L1a = {H1AGG, 512, 512, 768, nullptr, 0, 0, B1 + 768, 1536, xw1, 768, b1c, nullptr,
                 NN, 768, 0, nullptr, nullptr, nullptr, 6, RPG};
    combo<<<g2 + g6, blk, 0, stream>>>(C0p, g2, L1a, g6, dummy);

    // ---- D: agg(h0f→H0AGG)  (feeds L1b_t and L0_{t+1}) ----
    agg_h16<<<agg_grid, blk, 0, stream>>>(h0f, offs, esrc, H0AGG);

    // ---- E: L1b_t (H0AGG×Wx1, Cacc=xw1, fused r/u) ∥ OP_{t-1} ----
    GemmP L1b = {H0AGG, 512, 512, 768, nullptr, 0, 0, B1, 1536, xw1, 768, nullptr, xw1,
                 NN, 768, 1, h1c, nullptr, rhf16, 6, RPG};
    GemmP OPp = {h1f, 256, 256, 256, nullptr, 0, 0, Bo, 256,
                 out + (size_t)(t > 0 ? t - 1 : 0) * NN * FOUT, FOUT, bo, nullptr,
                 NN, 256, 0, nullptr, nullptr, nullptr, 1, RPG};
    if (t == 0)
      combo<<<g6, blk, 0, stream>>>(L1b, g6, dummy, 0, dummy);
    else
      combo<<<g6 + g1, blk, 0, stream>>>(L1b, g6, OPp, g1, dummy);

    // ---- F: agg(rhf16→RHAGG)  (feeds C1_t in next step's A) ----
    agg_h16<<<agg_grid, blk, 0, stream>>>(rhf16, offs, esrc, RHAGG);
  }

  // epilogue: C1_{T-1}, then OP_{T-1}
  GemmP C1f = {RHAGG, 512, 512, 768, nullptr, 0, 0, B1h, 768, xw1, 768, nullptr, nullptr,
               NN, 768, 2, h1c, h1f, nullptr, 2, RPG};
  combo<<<g2, blk, 0, stream>>>(C1f, g2, dummy, 0, dummy);
  GemmP OPl = {h1f, 256, 256, 256, nullptr, 0, 0, Bo, 256,
               out + (size_t)(T_STEPS - 1) * NN * FOUT, FOUT, bo, nullptr,
               NN, 256, 0, nullptr, nullptr, nullptr, 1, RPG};
  combo<<<g1, blk, 0, stream>>>(OPl, g1, dummy, 0, dummy);
}